// Round 1
// baseline (664.767 us; speedup 1.0000x reference)
//
#include <hip/hip_runtime.h>

#define NB 4
#define NN 1024
#define NCCH 128
#define NH 64
#define NW 64
#define NHW 4096

// (8*sqrt(2)+0.1)^2 in double, rounded to f32 like the reference comparison
constexpr float RADIUS2 = 130.27274173013714f;

// ---------------------------------------------------------------------------
// 4 nearest grid-cell centers of point (x,y). Cells at ((i+0.5)*8,(j+0.5)*8),
// i,j in [0,64). Top-4 always lies in a clamped >=4-wide window around
// floor(x/8-0.5). Strict '<' + increasing-linear-id iteration replicates
// jax.lax.top_k tie-breaking (lowest index wins).
// ---------------------------------------------------------------------------
__device__ __forceinline__ void nearest4(float x, float y, int out_ids[4]) {
    float u = x * 0.125f - 0.5f;
    float v = y * 0.125f - 0.5f;
    u = fminf(fmaxf(u, -1e6f), 1e6f);
    v = fminf(fmaxf(v, -1e6f), 1e6f);
    int iu = (int)floorf(u);
    int iv = (int)floorf(v);
    int xlo = min(max(iu - 2, 0), 60);
    int xhi = max(min(iu + 3, 63), 3);
    int ylo = min(max(iv - 2, 0), 60);
    int yhi = max(min(iv + 3, 63), 3);
    float bd0 = 1e30f, bd1 = 1e30f, bd2 = 1e30f, bd3 = 1e30f;
    int bi0 = 0, bi1 = 0, bi2 = 0, bi3 = 0;
    for (int yy = ylo; yy <= yhi; ++yy) {
        float dy = y - ((float)yy + 0.5f) * 8.0f;
        float dy2 = dy * dy;
        for (int xx = xlo; xx <= xhi; ++xx) {
            float dx = x - ((float)xx + 0.5f) * 8.0f;
            float d = dx * dx + dy2;
            int id = (yy << 6) | xx;
            if (d < bd3) {
                if (d < bd2) {
                    bd3 = bd2; bi3 = bi2;
                    if (d < bd1) {
                        bd2 = bd1; bi2 = bi1;
                        if (d < bd0) { bd1 = bd0; bi1 = bi0; bd0 = d; bi0 = id; }
                        else         { bd1 = d;  bi1 = id; }
                    } else { bd2 = d; bi2 = id; }
                } else { bd3 = d; bi3 = id; }
            }
        }
    }
    out_ids[0] = bi0; out_ids[1] = bi1; out_ids[2] = bi2; out_ids[3] = bi3;
}

// ---------------------------------------------------------------------------
// Kernel A: bilinear-sample desc2 at w_kp1, L2-normalize, positive_sim, and
// write transposed copies of kp1_desc / w_desc for the SOS GEMM B-operand.
// One wave (64 lanes) per keypoint, 2 channels per lane.
// ---------------------------------------------------------------------------
__global__ __launch_bounds__(256) void sample_kernel(
    const float* __restrict__ kp1, const float* __restrict__ w_kp1,
    const float* __restrict__ kp1_desc, const float* __restrict__ desc2,
    float* __restrict__ w_desc, float* __restrict__ kp1T,
    float* __restrict__ wT, float* __restrict__ pos_sim)
{
    int lane = threadIdx.x & 63;
    int wid = blockIdx.x * 4 + (threadIdx.x >> 6);
    if (wid >= NB * NN) return;
    int b = wid >> 10, n = wid & (NN - 1);

    float px = w_kp1[wid * 2 + 0], py = w_kp1[wid * 2 + 1];
    float fx = px * 0.125f - 0.5f, fy = py * 0.125f - 0.5f;
    float fx0 = floorf(fx), fy0 = floorf(fy);
    float wx = fx - fx0, wy = fy - fy0;
    int x0 = min(max((int)fx0, 0), NW - 1);
    int x1 = min(x0 + 1, NW - 1);
    int y0 = min(max((int)fy0, 0), NH - 1);
    int y1 = min(y0 + 1, NH - 1);
    float w00 = (1.f - wx) * (1.f - wy), w01 = wx * (1.f - wy);
    float w10 = (1.f - wx) * wy,         w11 = wx * wy;
    int i00 = y0 * NW + x0, i01 = y0 * NW + x1;
    int i10 = y1 * NW + x0, i11 = y1 * NW + x1;

    const float* d2 = desc2 + (size_t)b * NCCH * NHW;
    const float* p0 = d2 + (size_t)lane * NHW;
    const float* p1 = d2 + (size_t)(lane + 64) * NHW;
    float o0 = w00 * p0[i00] + w01 * p0[i01] + w10 * p0[i10] + w11 * p0[i11];
    float o1 = w00 * p1[i00] + w01 * p1[i01] + w10 * p1[i10] + w11 * p1[i11];
    float nrm = o0 * o0 + o1 * o1;
    #pragma unroll
    for (int off = 32; off > 0; off >>= 1) nrm += __shfl_xor(nrm, off, 64);
    float inv = 1.0f / (sqrtf(nrm) + 1e-8f);
    o0 *= inv; o1 *= inv;

    float a0 = kp1_desc[(size_t)wid * NCCH + lane];
    float a1 = kp1_desc[(size_t)wid * NCCH + lane + 64];
    float dot = a0 * o0 + a1 * o1;
    #pragma unroll
    for (int off = 32; off > 0; off >>= 1) dot += __shfl_xor(dot, off, 64);

    w_desc[(size_t)wid * NCCH + lane] = o0;
    w_desc[(size_t)wid * NCCH + lane + 64] = o1;
    size_t tb = (size_t)b * NCCH * NN;
    kp1T[tb + (size_t)lane * NN + n] = a0;
    kp1T[tb + (size_t)(lane + 64) * NN + n] = a1;
    wT[tb + (size_t)lane * NN + n] = o0;
    wT[tb + (size_t)(lane + 64) * NN + n] = o1;
    if (lane == 0) pos_sim[wid] = 2.0f - 2.0f * dot;
}

// ---------------------------------------------------------------------------
// Kernel B: per keypoint, 4 nearest cells of kp1 -> warp each center by H ->
// 4 nearest cells of each warped center = 16 penalty cell ids.
// ---------------------------------------------------------------------------
__global__ __launch_bounds__(256) void mask_kernel(
    const float* __restrict__ kp1, const float* __restrict__ homo,
    int* __restrict__ mask_ids)
{
    int g = blockIdx.x * blockDim.x + threadIdx.x;
    if (g >= NB * NN) return;
    int b = g >> 10;
    float x = kp1[g * 2], y = kp1[g * 2 + 1];
    const float* H = homo + b * 9;
    int c4[4];
    nearest4(x, y, c4);
    int out[16];
    #pragma unroll
    for (int k = 0; k < 4; ++k) {
        int id = c4[k];
        float cx = ((float)(id & 63) + 0.5f) * 8.0f;
        float cy = ((float)(id >> 6) + 0.5f) * 8.0f;
        float q0 = H[0] * cx + H[1] * cy + H[2];
        float q1 = H[3] * cx + H[4] * cy + H[5];
        float q2 = H[6] * cx + H[7] * cy + H[8];
        float iz = 1.0f / (q2 + 1e-8f);
        nearest4(q0 * iz, q1 * iz, out + 4 * k);
    }
    #pragma unroll
    for (int k = 0; k < 16; ++k) mask_ids[(size_t)g * 16 + k] = out[k];
}

// ---------------------------------------------------------------------------
// Kernel C/D: fused  sim = 2 - 2*(A . Bt)  (+ penalty)  -> top-8 smallest/row.
// MODE 0 (FOS): penalty = +5 per occurrence in mask_ids[16]; output =
//               sum_k relu(pos - v_k + 1)^2 per row.
// MODE 1 (SOS): penalty = +5 where pair dist^2 <= RADIUS2; output = the 8
//               smallest values ascending (== reference's gathered sims,
//               since penalized (>=5) can never beat unpenalized (<=4)).
// Block: 16 rows x NCOLS, chunked by 256 cols; thread tile 4x4; per-thread
// running top-8 over a stride-16 column subset, merged per row at the end.
// ---------------------------------------------------------------------------
template<int MODE, int NCOLS>
__global__ __launch_bounds__(256) void simtop_kernel(
    const float* __restrict__ A, const float* __restrict__ Bt,
    const float* __restrict__ coords, const int* __restrict__ mask_ids,
    const float* __restrict__ pos_sim, float* __restrict__ outp)
{
    constexpr int ROWS = 16;
    constexpr int CHUNK = 256;
    constexpr int NCHUNK = NCOLS / CHUNK;

    __shared__ float sA[ROWS][NCCH];
    __shared__ float sChunk[ROWS][CHUNK + 1];
    __shared__ float sMerge[ROWS][130];
    __shared__ int   sMask[ROWS][16];
    __shared__ float sPos[ROWS];
    __shared__ float sCx[CHUNK], sCy[CHUNK];
    __shared__ float sRx[ROWS], sRy[ROWS];

    int tid = threadIdx.x;
    int b = blockIdx.x / (NN / ROWS);
    int rg = blockIdx.x % (NN / ROWS);
    int row0 = rg * ROWS;

    for (int e = tid; e < ROWS * NCCH; e += 256) {
        int r = e >> 7, c = e & (NCCH - 1);
        sA[r][c] = A[((size_t)b * NN + row0 + r) * NCCH + c];
    }
    if (MODE == 0) {
        if (tid < ROWS * 16)
            sMask[tid >> 4][tid & 15] =
                mask_ids[((size_t)b * NN + row0 + (tid >> 4)) * 16 + (tid & 15)];
        if (tid < ROWS) sPos[tid] = pos_sim[b * NN + row0 + tid];
    } else {
        if (tid < ROWS) {
            sRx[tid] = coords[((size_t)b * NN + row0 + tid) * 2];
            sRy[tid] = coords[((size_t)b * NN + row0 + tid) * 2 + 1];
        }
    }

    float loc[8];
    #pragma unroll
    for (int k = 0; k < 8; ++k) loc[k] = 1e30f;

    int lane = tid & 63, wg = tid >> 6;
    const float* bp = Bt + (size_t)b * NCCH * NCOLS + 4 * lane;
    int srow = tid & 15, sgrp = tid >> 4;

    for (int ch = 0; ch < NCHUNK; ++ch) {
        int cbase = ch * CHUNK;
        __syncthreads();

        float acc[4][4];
        #pragma unroll
        for (int i = 0; i < 4; ++i)
            #pragma unroll
            for (int j = 0; j < 4; ++j) acc[i][j] = 0.f;

        const float* bptr = bp + cbase;
        for (int c = 0; c < NCCH; c += 4) {
            float4 b0 = *(const float4*)(bptr + (size_t)(c + 0) * NCOLS);
            float4 b1 = *(const float4*)(bptr + (size_t)(c + 1) * NCOLS);
            float4 b2 = *(const float4*)(bptr + (size_t)(c + 2) * NCOLS);
            float4 b3 = *(const float4*)(bptr + (size_t)(c + 3) * NCOLS);
            #pragma unroll
            for (int i = 0; i < 4; ++i) {
                float4 aq = *(const float4*)&sA[wg * 4 + i][c];
                acc[i][0] += aq.x * b0.x + aq.y * b1.x + aq.z * b2.x + aq.w * b3.x;
                acc[i][1] += aq.x * b0.y + aq.y * b1.y + aq.z * b2.y + aq.w * b3.y;
                acc[i][2] += aq.x * b0.z + aq.y * b1.z + aq.z * b2.z + aq.w * b3.z;
                acc[i][3] += aq.x * b0.w + aq.y * b1.w + aq.z * b2.w + aq.w * b3.w;
            }
        }
        #pragma unroll
        for (int i = 0; i < 4; ++i)
            #pragma unroll
            for (int j = 0; j < 4; ++j)
                sChunk[wg * 4 + i][4 * lane + j] = 2.0f - 2.0f * acc[i][j];
        __syncthreads();

        if (MODE == 0) {
            int r = tid >> 4, k = tid & 15;
            int id = sMask[r][k] - cbase;
            if (id >= 0 && id < CHUNK) atomicAdd(&sChunk[r][id], 5.0f);
        } else {
            sCx[tid] = coords[((size_t)b * NN + cbase + tid) * 2];
            sCy[tid] = coords[((size_t)b * NN + cbase + tid) * 2 + 1];
        }
        __syncthreads();

        float rx = 0.f, ry = 0.f;
        if (MODE == 1) { rx = sRx[srow]; ry = sRy[srow]; }
        #pragma unroll
        for (int j = 0; j < 16; ++j) {
            int cl = sgrp + 16 * j;
            float v = sChunk[srow][cl];
            if (MODE == 1) {
                float dx = rx - sCx[cl], dy = ry - sCy[cl];
                if (dx * dx + dy * dy <= RADIUS2) v += 5.0f;
            }
            if (v < loc[7]) {
                loc[7] = v;
                #pragma unroll
                for (int p = 7; p > 0; --p) {
                    if (loc[p - 1] > loc[p]) {
                        float t = loc[p - 1]; loc[p - 1] = loc[p]; loc[p] = t;
                    }
                }
            }
        }
    }

    #pragma unroll
    for (int k = 0; k < 8; ++k) sMerge[srow][sgrp * 8 + k] = loc[k];
    __syncthreads();

    if (tid < ROWS) {
        float sel[8];
        float* m = sMerge[tid];
        #pragma unroll
        for (int k = 0; k < 8; ++k) {
            float best = 1e30f; int bi = 0;
            for (int q = 0; q < 128; ++q) {
                float vv = m[q];
                if (vv < best) { best = vv; bi = q; }
            }
            m[bi] = 1e30f;
            sel[k] = best;
        }
        if (MODE == 0) {
            float p = sPos[tid];
            float s = 0.f;
            #pragma unroll
            for (int k = 0; k < 8; ++k) {
                float h = fmaxf(p - sel[k] + 1.0f, 0.f);
                s += h * h;
            }
            outp[b * NN + row0 + tid] = s;
        } else {
            #pragma unroll
            for (int k = 0; k < 8; ++k)
                outp[((size_t)(b * NN + row0 + tid)) * 8 + k] = sel[k];
        }
    }
}

// ---------------------------------------------------------------------------
// Kernel E: final reduction -> scalar loss
// ---------------------------------------------------------------------------
__global__ __launch_bounds__(256) void finalize_kernel(
    const float* __restrict__ fos_row, const float* __restrict__ sA8,
    const float* __restrict__ sB8, float* __restrict__ outp)
{
    __shared__ float sf[256], ss[256];
    int t = threadIdx.x;
    float f = 0.f, s = 0.f;
    for (int i = t; i < NB * NN; i += 256) {
        f += fos_row[i];
        float acc = 0.f;
        #pragma unroll
        for (int k = 0; k < 8; ++k) {
            float d = sA8[(size_t)i * 8 + k] - sB8[(size_t)i * 8 + k];
            acc += d * d;
        }
        s += sqrtf(acc);
    }
    sf[t] = f; ss[t] = s;
    __syncthreads();
    for (int o = 128; o > 0; o >>= 1) {
        if (t < o) { sf[t] += sf[t + o]; ss[t] += ss[t + o]; }
        __syncthreads();
    }
    if (t == 0)
        outp[0] = sf[0] / (float)(NB * NN * 8) + ss[0] / (float)(NB * NN);
}

extern "C" void kernel_launch(void* const* d_in, const int* in_sizes, int n_in,
                              void* d_out, int out_size, void* d_ws, size_t ws_size,
                              hipStream_t stream) {
    const float* kp1      = (const float*)d_in[0];
    const float* w_kp1    = (const float*)d_in[1];
    const float* kp1_desc = (const float*)d_in[2];
    const float* desc2    = (const float*)d_in[3];
    const float* homo     = (const float*)d_in[4];
    float* outp = (float*)d_out;

    char* ws = (char*)d_ws;
    size_t o = 0;
    float* w_desc  = (float*)(ws + o); o += (size_t)NB * NN * NCCH * 4;
    float* kp1T    = (float*)(ws + o); o += (size_t)NB * NCCH * NN * 4;
    float* wT      = (float*)(ws + o); o += (size_t)NB * NCCH * NN * 4;
    float* pos_sim = (float*)(ws + o); o += (size_t)NB * NN * 4;
    float* fos_row = (float*)(ws + o); o += (size_t)NB * NN * 4;
    float* sosA    = (float*)(ws + o); o += (size_t)NB * NN * 8 * 4;
    float* sosB    = (float*)(ws + o); o += (size_t)NB * NN * 8 * 4;
    int*   mask_id = (int*)(ws + o);   o += (size_t)NB * NN * 16 * 4;

    sample_kernel<<<NB * NN / 4, 256, 0, stream>>>(kp1, w_kp1, kp1_desc, desc2,
                                                   w_desc, kp1T, wT, pos_sim);
    mask_kernel<<<NB * NN / 256, 256, 0, stream>>>(kp1, homo, mask_id);
    simtop_kernel<0, NHW><<<NB * (NN / 16), 256, 0, stream>>>(
        kp1_desc, desc2, nullptr, mask_id, pos_sim, fos_row);
    simtop_kernel<1, NN><<<NB * (NN / 16), 256, 0, stream>>>(
        kp1_desc, kp1T, kp1, nullptr, nullptr, sosA);
    simtop_kernel<1, NN><<<NB * (NN / 16), 256, 0, stream>>>(
        w_desc, wT, w_kp1, nullptr, nullptr, sosB);
    finalize_kernel<<<1, 256, 0, stream>>>(fos_row, sosA, sosB, outp);
}

// Round 3
// 248.696 us; speedup vs baseline: 2.6730x; 2.6730x over previous
//
#include <hip/hip_runtime.h>

#define NB 4
#define NN 1024
#define NCCH 128
#define NH 64
#define NW 64
#define NHW 4096

// (8*sqrt(2)+0.1)^2 in double, rounded to f32 like the reference comparison
constexpr float RADIUS2 = 130.27274173013714f;

// ---------------------------------------------------------------------------
// bitonic partial merge: two ascending sorted-8 lists -> smallest 8, ascending.
// All indices static after unroll (no scratch spill, rule #20).
// ---------------------------------------------------------------------------
__device__ __forceinline__ void bsort8(float* v) {
    #pragma unroll
    for (int d = 4; d >= 1; d >>= 1) {
        #pragma unroll
        for (int i = 0; i < 8; ++i) {
            if ((i & d) == 0) {
                float x = v[i], y = v[i + d];
                v[i] = fminf(x, y);
                v[i + d] = fmaxf(x, y);
            }
        }
    }
}
__device__ __forceinline__ void merge8(const float* a, const float* b, float* o) {
    #pragma unroll
    for (int k = 0; k < 8; ++k) o[k] = fminf(a[k], b[7 - k]);
    bsort8(o);
}

// ---------------------------------------------------------------------------
// 4 nearest grid-cell centers of point (x,y). Strict '<' + increasing linear
// id replicates jax.lax.top_k tie-breaking.
// ---------------------------------------------------------------------------
__device__ __forceinline__ void nearest4(float x, float y, int out_ids[4]) {
    float u = x * 0.125f - 0.5f;
    float v = y * 0.125f - 0.5f;
    u = fminf(fmaxf(u, -1e6f), 1e6f);
    v = fminf(fmaxf(v, -1e6f), 1e6f);
    int iu = (int)floorf(u);
    int iv = (int)floorf(v);
    int xlo = min(max(iu - 2, 0), 60);
    int xhi = max(min(iu + 3, 63), 3);
    int ylo = min(max(iv - 2, 0), 60);
    int yhi = max(min(iv + 3, 63), 3);
    float bd0 = 1e30f, bd1 = 1e30f, bd2 = 1e30f, bd3 = 1e30f;
    int bi0 = 0, bi1 = 0, bi2 = 0, bi3 = 0;
    for (int yy = ylo; yy <= yhi; ++yy) {
        float dy = y - ((float)yy + 0.5f) * 8.0f;
        float dy2 = dy * dy;
        for (int xx = xlo; xx <= xhi; ++xx) {
            float dx = x - ((float)xx + 0.5f) * 8.0f;
            float d = dx * dx + dy2;
            int id = (yy << 6) | xx;
            if (d < bd3) {
                if (d < bd2) {
                    bd3 = bd2; bi3 = bi2;
                    if (d < bd1) {
                        bd2 = bd1; bi2 = bi1;
                        if (d < bd0) { bd1 = bd0; bi1 = bi0; bd0 = d; bi0 = id; }
                        else         { bd1 = d;  bi1 = id; }
                    } else { bd2 = d; bi2 = id; }
                } else { bd3 = d; bi3 = id; }
            }
        }
    }
    out_ids[0] = bi0; out_ids[1] = bi1; out_ids[2] = bi2; out_ids[3] = bi3;
}

// ---------------------------------------------------------------------------
// Kernel A: bilinear-sample desc2 at w_kp1, L2-normalize, positive_sim, and
// write transposed copies of kp1_desc / w_desc for the SOS GEMM B-operand.
// ---------------------------------------------------------------------------
__global__ __launch_bounds__(256) void sample_kernel(
    const float* __restrict__ kp1, const float* __restrict__ w_kp1,
    const float* __restrict__ kp1_desc, const float* __restrict__ desc2,
    float* __restrict__ w_desc, float* __restrict__ kp1T,
    float* __restrict__ wT, float* __restrict__ pos_sim)
{
    int lane = threadIdx.x & 63;
    int wid = blockIdx.x * 4 + (threadIdx.x >> 6);
    if (wid >= NB * NN) return;
    int b = wid >> 10, n = wid & (NN - 1);

    float px = w_kp1[wid * 2 + 0], py = w_kp1[wid * 2 + 1];
    float fx = px * 0.125f - 0.5f, fy = py * 0.125f - 0.5f;
    float fx0 = floorf(fx), fy0 = floorf(fy);
    float wx = fx - fx0, wy = fy - fy0;
    int x0 = min(max((int)fx0, 0), NW - 1);
    int x1 = min(x0 + 1, NW - 1);
    int y0 = min(max((int)fy0, 0), NH - 1);
    int y1 = min(y0 + 1, NH - 1);
    float w00 = (1.f - wx) * (1.f - wy), w01 = wx * (1.f - wy);
    float w10 = (1.f - wx) * wy,         w11 = wx * wy;
    int i00 = y0 * NW + x0, i01 = y0 * NW + x1;
    int i10 = y1 * NW + x0, i11 = y1 * NW + x1;

    const float* d2 = desc2 + (size_t)b * NCCH * NHW;
    const float* p0 = d2 + (size_t)lane * NHW;
    const float* p1 = d2 + (size_t)(lane + 64) * NHW;
    float o0 = w00 * p0[i00] + w01 * p0[i01] + w10 * p0[i10] + w11 * p0[i11];
    float o1 = w00 * p1[i00] + w01 * p1[i01] + w10 * p1[i10] + w11 * p1[i11];
    float nrm = o0 * o0 + o1 * o1;
    #pragma unroll
    for (int off = 32; off > 0; off >>= 1) nrm += __shfl_xor(nrm, off, 64);
    float inv = 1.0f / (sqrtf(nrm) + 1e-8f);
    o0 *= inv; o1 *= inv;

    float a0 = kp1_desc[(size_t)wid * NCCH + lane];
    float a1 = kp1_desc[(size_t)wid * NCCH + lane + 64];
    float dot = a0 * o0 + a1 * o1;
    #pragma unroll
    for (int off = 32; off > 0; off >>= 1) dot += __shfl_xor(dot, off, 64);

    w_desc[(size_t)wid * NCCH + lane] = o0;
    w_desc[(size_t)wid * NCCH + lane + 64] = o1;
    size_t tb = (size_t)b * NCCH * NN;
    kp1T[tb + (size_t)lane * NN + n] = a0;
    kp1T[tb + (size_t)(lane + 64) * NN + n] = a1;
    wT[tb + (size_t)lane * NN + n] = o0;
    wT[tb + (size_t)(lane + 64) * NN + n] = o1;
    if (lane == 0) pos_sim[wid] = 2.0f - 2.0f * dot;
}

// ---------------------------------------------------------------------------
// Kernel B: 16 penalty cell ids per keypoint (4 nearest of kp1 -> warp -> 4
// nearest each).
// ---------------------------------------------------------------------------
__global__ __launch_bounds__(256) void mask_kernel(
    const float* __restrict__ kp1, const float* __restrict__ homo,
    int* __restrict__ mask_ids)
{
    int g = blockIdx.x * blockDim.x + threadIdx.x;
    if (g >= NB * NN) return;
    int b = g >> 10;
    float x = kp1[g * 2], y = kp1[g * 2 + 1];
    const float* H = homo + b * 9;
    int c4[4];
    nearest4(x, y, c4);
    int out[16];
    #pragma unroll
    for (int k = 0; k < 4; ++k) {
        int id = c4[k];
        float cx = ((float)(id & 63) + 0.5f) * 8.0f;
        float cy = ((float)(id >> 6) + 0.5f) * 8.0f;
        float q0 = H[0] * cx + H[1] * cy + H[2];
        float q1 = H[3] * cx + H[4] * cy + H[5];
        float q2 = H[6] * cx + H[7] * cy + H[8];
        float iz = 1.0f / (q2 + 1e-8f);
        nearest4(q0 * iz, q1 * iz, out + 4 * k);
    }
    #pragma unroll
    for (int k = 0; k < 16; ++k) mask_ids[(size_t)g * 16 + k] = out[k];
}

// ---------------------------------------------------------------------------
// Fused sim+top8 kernel, column-split for occupancy.
//   blocks [0,1024):    FOS  (A=kp1_desc, B=desc2, ncols=4096, 4 col-blocks)
//   blocks [1024,1536): SOS-A (A=kp1_desc, B=kp1T, ncols=1024, 2 col-blocks)
//   blocks [1536,2048): SOS-B (A=w_desc,  B=wT,   ncols=1024, 2 col-blocks)
// Each block: 16 rows x colspan, emits sorted partial top-8 per row.
// ---------------------------------------------------------------------------
__global__ __launch_bounds__(256, 4) void simtop_fused(
    const float* __restrict__ kp1_desc, const float* __restrict__ desc2,
    const float* __restrict__ w_desc, const float* __restrict__ kp1T,
    const float* __restrict__ wT, const float* __restrict__ kp1,
    const float* __restrict__ w_kp1, const int* __restrict__ mask_ids,
    float* __restrict__ fosP, float* __restrict__ sosAP,
    float* __restrict__ sosBP)
{
    __shared__ float sA[16][NCCH];       // 8 KB
    __shared__ float sChunk[16][257];    // 16.4 KB (aliased as merge buffer)
    __shared__ int   sMask[16][16];
    __shared__ float sCx[256], sCy[256];
    __shared__ float sRx[16], sRy[16];

    int tid = threadIdx.x;
    int bid = blockIdx.x;

    int mode, cs, rg, b, ncols, nchunk, colbase, outStride;
    const float* A; const float* Bt; const float* coords = nullptr;
    float* outP;
    if (bid < 1024) {
        mode = 0; cs = bid & 3; rg = (bid >> 2) & 63; b = bid >> 8;
        ncols = NHW; nchunk = 4; colbase = cs * 1024;
        A = kp1_desc; Bt = desc2; outP = fosP; outStride = 32;
    } else if (bid < 1536) {
        int id = bid - 1024;
        mode = 1; cs = id & 1; rg = (id >> 1) & 63; b = id >> 7;
        ncols = NN; nchunk = 2; colbase = cs * 512;
        A = kp1_desc; Bt = kp1T; coords = kp1; outP = sosAP; outStride = 16;
    } else {
        int id = bid - 1536;
        mode = 2; cs = id & 1; rg = (id >> 1) & 63; b = id >> 7;
        ncols = NN; nchunk = 2; colbase = cs * 512;
        A = w_desc; Bt = wT; coords = w_kp1; outP = sosBP; outStride = 16;
    }
    int row0 = rg * 16;

    // stage A tile (16 x 128), vectorized
    {
        int r = tid >> 4, c = (tid & 15) * 8;
        const float* src = A + ((size_t)b * NN + row0 + r) * NCCH + c;
        float4 v0 = *(const float4*)(src);
        float4 v1 = *(const float4*)(src + 4);
        *(float4*)&sA[r][c] = v0;
        *(float4*)&sA[r][c + 4] = v1;
    }
    if (mode == 0) {
        sMask[tid >> 4][tid & 15] =
            mask_ids[((size_t)b * NN + row0 + (tid >> 4)) * 16 + (tid & 15)];
    } else if (tid < 16) {
        sRx[tid] = coords[((size_t)b * NN + row0 + tid) * 2];
        sRy[tid] = coords[((size_t)b * NN + row0 + tid) * 2 + 1];
    }

    float loc[8];
    #pragma unroll
    for (int k = 0; k < 8; ++k) loc[k] = 1e30f;

    int lane = tid & 63, wg = tid >> 6;
    int srow = tid & 15, sgrp = tid >> 4;
    const float* bbase = Bt + (size_t)b * NCCH * ncols + colbase + 4 * lane;

    for (int ch = 0; ch < nchunk; ++ch) {
        int cglob = colbase + ch * 256;
        __syncthreads();

        float acc[4][4];
        #pragma unroll
        for (int i = 0; i < 4; ++i)
            #pragma unroll
            for (int j = 0; j < 4; ++j) acc[i][j] = 0.f;

        const float* bptr = bbase + ch * 256;
        #pragma unroll 2
        for (int c = 0; c < NCCH; c += 4) {
            float4 b0 = *(const float4*)(bptr);
            float4 b1 = *(const float4*)(bptr + ncols);
            float4 b2 = *(const float4*)(bptr + 2 * (size_t)ncols);
            float4 b3 = *(const float4*)(bptr + 3 * (size_t)ncols);
            bptr += 4 * (size_t)ncols;
            #pragma unroll
            for (int i = 0; i < 4; ++i) {
                float4 aq = *(const float4*)&sA[wg * 4 + i][c];
                acc[i][0] += aq.x * b0.x + aq.y * b1.x + aq.z * b2.x + aq.w * b3.x;
                acc[i][1] += aq.x * b0.y + aq.y * b1.y + aq.z * b2.y + aq.w * b3.y;
                acc[i][2] += aq.x * b0.z + aq.y * b1.z + aq.z * b2.z + aq.w * b3.z;
                acc[i][3] += aq.x * b0.w + aq.y * b1.w + aq.z * b2.w + aq.w * b3.w;
            }
        }
        #pragma unroll
        for (int i = 0; i < 4; ++i)
            #pragma unroll
            for (int j = 0; j < 4; ++j)
                sChunk[wg * 4 + i][4 * lane + j] = 2.0f - 2.0f * acc[i][j];
        __syncthreads();

        if (mode == 0) {
            int r = tid >> 4, k = tid & 15;
            int id = sMask[r][k] - cglob;
            if (id >= 0 && id < 256) atomicAdd(&sChunk[r][id], 5.0f);
        } else {
            sCx[tid] = coords[((size_t)b * NN + cglob + tid) * 2];
            sCy[tid] = coords[((size_t)b * NN + cglob + tid) * 2 + 1];
        }
        __syncthreads();

        float rx = 0.f, ry = 0.f;
        if (mode != 0) { rx = sRx[srow]; ry = sRy[srow]; }
        #pragma unroll
        for (int j = 0; j < 16; ++j) {
            int cl = sgrp * 16 + j;      // consecutive-16 ownership: 2-way banks
            float v = sChunk[srow][cl];
            if (mode != 0) {
                float dx = rx - sCx[cl], dy = ry - sCy[cl];
                if (dx * dx + dy * dy <= RADIUS2) v += 5.0f;
            }
            if (v < loc[7]) {
                loc[7] = v;
                #pragma unroll
                for (int p = 7; p > 0; --p) {
                    if (loc[p - 1] > loc[p]) {
                        float t = loc[p - 1]; loc[p - 1] = loc[p]; loc[p] = t;
                    }
                }
            }
        }
    }

    // parallel tree merge of the 16 per-thread sorted lists per row
    __syncthreads();
    float* mg = &sChunk[0][0];           // [16][130] alias (2080 < 4112 floats)
    #pragma unroll
    for (int k = 0; k < 8; ++k) mg[srow * 130 + sgrp * 8 + k] = loc[k];
    __syncthreads();
    #pragma unroll
    for (int step = 1; step < 16; step <<= 1) {
        if ((sgrp & (2 * step - 1)) == 0) {
            float a[8], bb[8], o[8];
            #pragma unroll
            for (int k = 0; k < 8; ++k) {
                a[k]  = mg[srow * 130 + sgrp * 8 + k];
                bb[k] = mg[srow * 130 + (sgrp + step) * 8 + k];
            }
            merge8(a, bb, o);
            #pragma unroll
            for (int k = 0; k < 8; ++k) mg[srow * 130 + sgrp * 8 + k] = o[k];
        }
        __syncthreads();
    }
    if (tid < 16) {
        size_t row = (size_t)b * NN + row0 + tid;
        #pragma unroll
        for (int k = 0; k < 8; ++k)
            outP[row * outStride + cs * 8 + k] = mg[tid * 130 + k];
    }
}

// ---------------------------------------------------------------------------
// Per-row finalize: merge partial top-8 lists, hinge (FOS) and sqrt-diff (SOS)
// ---------------------------------------------------------------------------
__global__ __launch_bounds__(256) void frow_kernel(
    const float* __restrict__ fosP, const float* __restrict__ sosAP,
    const float* __restrict__ sosBP, const float* __restrict__ pos_sim,
    float* __restrict__ frow, float* __restrict__ srow)
{
    int row = blockIdx.x * 256 + threadIdx.x;
    if (row >= NB * NN) return;

    float l0[8], l1[8], l2[8], l3[8], t0[8], t1[8], m[8];
    const float4* fp = (const float4*)(fosP + (size_t)row * 32);
    float4 q;
    q = fp[0]; l0[0]=q.x; l0[1]=q.y; l0[2]=q.z; l0[3]=q.w;
    q = fp[1]; l0[4]=q.x; l0[5]=q.y; l0[6]=q.z; l0[7]=q.w;
    q = fp[2]; l1[0]=q.x; l1[1]=q.y; l1[2]=q.z; l1[3]=q.w;
    q = fp[3]; l1[4]=q.x; l1[5]=q.y; l1[6]=q.z; l1[7]=q.w;
    q = fp[4]; l2[0]=q.x; l2[1]=q.y; l2[2]=q.z; l2[3]=q.w;
    q = fp[5]; l2[4]=q.x; l2[5]=q.y; l2[6]=q.z; l2[7]=q.w;
    q = fp[6]; l3[0]=q.x; l3[1]=q.y; l3[2]=q.z; l3[3]=q.w;
    q = fp[7]; l3[4]=q.x; l3[5]=q.y; l3[6]=q.z; l3[7]=q.w;
    merge8(l0, l1, t0); merge8(l2, l3, t1); merge8(t0, t1, m);

    float p = pos_sim[row], fs = 0.f;
    #pragma unroll
    for (int k = 0; k < 8; ++k) {
        float h = fmaxf(p - m[k] + 1.0f, 0.f);
        fs += h * h;
    }

    const float4* ap = (const float4*)(sosAP + (size_t)row * 16);
    q = ap[0]; l0[0]=q.x; l0[1]=q.y; l0[2]=q.z; l0[3]=q.w;
    q = ap[1]; l0[4]=q.x; l0[5]=q.y; l0[6]=q.z; l0[7]=q.w;
    q = ap[2]; l1[0]=q.x; l1[1]=q.y; l1[2]=q.z; l1[3]=q.w;
    q = ap[3]; l1[4]=q.x; l1[5]=q.y; l1[6]=q.z; l1[7]=q.w;
    merge8(l0, l1, t0);
    const float4* bp = (const float4*)(sosBP + (size_t)row * 16);
    q = bp[0]; l2[0]=q.x; l2[1]=q.y; l2[2]=q.z; l2[3]=q.w;
    q = bp[1]; l2[4]=q.x; l2[5]=q.y; l2[6]=q.z; l2[7]=q.w;
    q = bp[2]; l3[0]=q.x; l3[1]=q.y; l3[2]=q.z; l3[3]=q.w;
    q = bp[3]; l3[4]=q.x; l3[5]=q.y; l3[6]=q.z; l3[7]=q.w;
    merge8(l2, l3, t1);

    float acc = 0.f;
    #pragma unroll
    for (int k = 0; k < 8; ++k) {
        float d = t0[k] - t1[k];
        acc += d * d;
    }
    frow[row] = fs;
    srow[row] = sqrtf(acc);
}

__global__ __launch_bounds__(256) void freduce_kernel(
    const float* __restrict__ frow, const float* __restrict__ srow,
    float* __restrict__ outp)
{
    __shared__ float sf[256], ss[256];
    int t = threadIdx.x;
    float f = 0.f, s = 0.f;
    for (int i = t; i < NB * NN; i += 256) { f += frow[i]; s += srow[i]; }
    sf[t] = f; ss[t] = s;
    __syncthreads();
    for (int o = 128; o > 0; o >>= 1) {
        if (t < o) { sf[t] += sf[t + o]; ss[t] += ss[t + o]; }
        __syncthreads();
    }
    if (t == 0)
        outp[0] = sf[0] / (float)(NB * NN * 8) + ss[0] / (float)(NB * NN);
}

extern "C" void kernel_launch(void* const* d_in, const int* in_sizes, int n_in,
                              void* d_out, int out_size, void* d_ws, size_t ws_size,
                              hipStream_t stream) {
    const float* kp1      = (const float*)d_in[0];
    const float* w_kp1    = (const float*)d_in[1];
    const float* kp1_desc = (const float*)d_in[2];
    const float* desc2    = (const float*)d_in[3];
    const float* homo     = (const float*)d_in[4];
    float* outp = (float*)d_out;

    char* ws = (char*)d_ws;
    size_t o = 0;
    float* w_desc  = (float*)(ws + o); o += (size_t)NB * NN * NCCH * 4;
    float* kp1T    = (float*)(ws + o); o += (size_t)NB * NCCH * NN * 4;
    float* wT      = (float*)(ws + o); o += (size_t)NB * NCCH * NN * 4;
    float* pos_sim = (float*)(ws + o); o += (size_t)NB * NN * 4;
    float* fosP    = (float*)(ws + o); o += (size_t)NB * NN * 32 * 4;
    float* sosAP   = (float*)(ws + o); o += (size_t)NB * NN * 16 * 4;
    float* sosBP   = (float*)(ws + o); o += (size_t)NB * NN * 16 * 4;
    float* frow    = (float*)(ws + o); o += (size_t)NB * NN * 4;
    float* srow    = (float*)(ws + o); o += (size_t)NB * NN * 4;
    int*   mask_id = (int*)(ws + o);   o += (size_t)NB * NN * 16 * 4;

    sample_kernel<<<NB * NN / 4, 256, 0, stream>>>(kp1, w_kp1, kp1_desc, desc2,
                                                   w_desc, kp1T, wT, pos_sim);
    mask_kernel<<<NB * NN / 256, 256, 0, stream>>>(kp1, homo, mask_id);
    simtop_fused<<<2048, 256, 0, stream>>>(kp1_desc, desc2, w_desc, kp1T, wT,
                                           kp1, w_kp1, mask_id,
                                           fosP, sosAP, sosBP);
    frow_kernel<<<16, 256, 0, stream>>>(fosP, sosAP, sosBP, pos_sim, frow, srow);
    freduce_kernel<<<1, 256, 0, stream>>>(frow, srow, outp);
}

// Round 4
// 211.842 us; speedup vs baseline: 3.1380x; 1.1740x over previous
//
#include <hip/hip_runtime.h>

#define NB 4
#define NN 1024
#define NCCH 128
#define NH 64
#define NW 64
#define NHW 4096

// (8*sqrt(2)+0.1)^2
constexpr float RADIUS2 = 130.27274173013714f;

typedef __attribute__((ext_vector_type(8))) short short8v;   // 8 bf16 = 4 VGPR
typedef __attribute__((ext_vector_type(4))) float f32x4;

__device__ __forceinline__ unsigned short f2bf(float f) {   // RNE f32->bf16
    unsigned u = __float_as_uint(f);
    unsigned r = u + 0x7FFFu + ((u >> 16) & 1u);
    return (unsigned short)(r >> 16);
}
__device__ __forceinline__ float bf2f(unsigned short h) {
    return __uint_as_float(((unsigned)h) << 16);
}

// ---------------------------------------------------------------------------
// bitonic partial merge: two ascending sorted-8 lists -> smallest 8 ascending
// ---------------------------------------------------------------------------
__device__ __forceinline__ void bsort8(float* v) {
    #pragma unroll
    for (int d = 4; d >= 1; d >>= 1) {
        #pragma unroll
        for (int i = 0; i < 8; ++i) {
            if ((i & d) == 0) {
                float x = v[i], y = v[i + d];
                v[i] = fminf(x, y);
                v[i + d] = fmaxf(x, y);
            }
        }
    }
}
__device__ __forceinline__ void merge8(const float* a, const float* b, float* o) {
    #pragma unroll
    for (int k = 0; k < 8; ++k) o[k] = fminf(a[k], b[7 - k]);
    bsort8(o);
}

// ---------------------------------------------------------------------------
// 4 nearest grid-cell centers; strict '<' + increasing linear id replicates
// jax.lax.top_k tie-breaking.
// ---------------------------------------------------------------------------
__device__ __forceinline__ void nearest4(float x, float y, int out_ids[4]) {
    float u = x * 0.125f - 0.5f;
    float v = y * 0.125f - 0.5f;
    u = fminf(fmaxf(u, -1e6f), 1e6f);
    v = fminf(fmaxf(v, -1e6f), 1e6f);
    int iu = (int)floorf(u);
    int iv = (int)floorf(v);
    int xlo = min(max(iu - 2, 0), 60);
    int xhi = max(min(iu + 3, 63), 3);
    int ylo = min(max(iv - 2, 0), 60);
    int yhi = max(min(iv + 3, 63), 3);
    float bd0 = 1e30f, bd1 = 1e30f, bd2 = 1e30f, bd3 = 1e30f;
    int bi0 = 0, bi1 = 0, bi2 = 0, bi3 = 0;
    for (int yy = ylo; yy <= yhi; ++yy) {
        float dy = y - ((float)yy + 0.5f) * 8.0f;
        float dy2 = dy * dy;
        for (int xx = xlo; xx <= xhi; ++xx) {
            float dx = x - ((float)xx + 0.5f) * 8.0f;
            float d = dx * dx + dy2;
            int id = (yy << 6) | xx;
            if (d < bd3) {
                if (d < bd2) {
                    bd3 = bd2; bi3 = bi2;
                    if (d < bd1) {
                        bd2 = bd1; bi2 = bi1;
                        if (d < bd0) { bd1 = bd0; bi1 = bi0; bd0 = d; bi0 = id; }
                        else         { bd1 = d;  bi1 = id; }
                    } else { bd2 = d; bi2 = id; }
                } else { bd3 = d; bi3 = id; }
            }
        }
    }
    out_ids[0] = bi0; out_ids[1] = bi1; out_ids[2] = bi2; out_ids[3] = bi3;
}

// ---------------------------------------------------------------------------
// Kernel A: bilinear-sample desc2 at w_kp1, L2-normalize, positive_sim, and
// bf16 hi/lo splits of kp1_desc (khi/klo) and w_desc (whi/wlo), row-major
// [B][N][C] — serves as both MFMA A-operand and SOS B-operand.
// ---------------------------------------------------------------------------
__global__ __launch_bounds__(256) void sample_kernel(
    const float* __restrict__ kp1, const float* __restrict__ w_kp1,
    const float* __restrict__ kp1_desc, const float* __restrict__ desc2,
    unsigned short* __restrict__ khi, unsigned short* __restrict__ klo,
    unsigned short* __restrict__ whi, unsigned short* __restrict__ wlo,
    float* __restrict__ pos_sim)
{
    int lane = threadIdx.x & 63;
    int wid = blockIdx.x * 4 + (threadIdx.x >> 6);
    if (wid >= NB * NN) return;
    int b = wid >> 10;

    float px = w_kp1[wid * 2 + 0], py = w_kp1[wid * 2 + 1];
    float fx = px * 0.125f - 0.5f, fy = py * 0.125f - 0.5f;
    float fx0 = floorf(fx), fy0 = floorf(fy);
    float wx = fx - fx0, wy = fy - fy0;
    int x0 = min(max((int)fx0, 0), NW - 1);
    int x1 = min(x0 + 1, NW - 1);
    int y0 = min(max((int)fy0, 0), NH - 1);
    int y1 = min(y0 + 1, NH - 1);
    float w00 = (1.f - wx) * (1.f - wy), w01 = wx * (1.f - wy);
    float w10 = (1.f - wx) * wy,         w11 = wx * wy;
    int i00 = y0 * NW + x0, i01 = y0 * NW + x1;
    int i10 = y1 * NW + x0, i11 = y1 * NW + x1;

    const float* d2 = desc2 + (size_t)b * NCCH * NHW;
    const float* p0 = d2 + (size_t)lane * NHW;
    const float* p1 = d2 + (size_t)(lane + 64) * NHW;
    float o0 = w00 * p0[i00] + w01 * p0[i01] + w10 * p0[i10] + w11 * p0[i11];
    float o1 = w00 * p1[i00] + w01 * p1[i01] + w10 * p1[i10] + w11 * p1[i11];
    float nrm = o0 * o0 + o1 * o1;
    #pragma unroll
    for (int off = 32; off > 0; off >>= 1) nrm += __shfl_xor(nrm, off, 64);
    float inv = 1.0f / (sqrtf(nrm) + 1e-8f);
    o0 *= inv; o1 *= inv;

    float a0 = kp1_desc[(size_t)wid * NCCH + lane];
    float a1 = kp1_desc[(size_t)wid * NCCH + lane + 64];
    float dot = a0 * o0 + a1 * o1;
    #pragma unroll
    for (int off = 32; off > 0; off >>= 1) dot += __shfl_xor(dot, off, 64);

    size_t base = (size_t)wid * NCCH;
    unsigned short h;
    h = f2bf(a0); khi[base + lane] = h;      klo[base + lane] = f2bf(a0 - bf2f(h));
    h = f2bf(a1); khi[base + lane + 64] = h; klo[base + lane + 64] = f2bf(a1 - bf2f(h));
    h = f2bf(o0); whi[base + lane] = h;      wlo[base + lane] = f2bf(o0 - bf2f(h));
    h = f2bf(o1); whi[base + lane + 64] = h; wlo[base + lane + 64] = f2bf(o1 - bf2f(h));
    if (lane == 0) pos_sim[wid] = 2.0f - 2.0f * dot;
}

// ---------------------------------------------------------------------------
// Kernel A2: desc2 [B][C][HW] -> bf16 hi/lo in [B][HW][C] layout (FOS MFMA
// B-operand: fragment loads become contiguous 16B in channel k).
// ---------------------------------------------------------------------------
__global__ __launch_bounds__(256) void d2split_kernel(
    const float* __restrict__ desc2,
    unsigned short* __restrict__ d2hi, unsigned short* __restrict__ d2lo)
{
    __shared__ float sT[64][130];
    int b = blockIdx.x >> 6;
    int hw0 = (blockIdx.x & 63) * 64;
    int t = threadIdx.x;
    int hwl = t & 63, cg = t >> 6;
    const float* src = desc2 + (size_t)b * NCCH * NHW + hw0 + hwl;
    #pragma unroll 4
    for (int i = 0; i < 32; ++i) {
        int c = cg * 32 + i;
        sT[hwl][c] = src[(size_t)c * NHW];
    }
    __syncthreads();
    int hw = t >> 2, cseg = (t & 3) * 32;
    unsigned short* dh = d2hi + ((size_t)b * NHW + hw0 + hw) * NCCH + cseg;
    unsigned short* dl = d2lo + ((size_t)b * NHW + hw0 + hw) * NCCH + cseg;
    #pragma unroll 4
    for (int i = 0; i < 32; ++i) {
        float f = sT[hw][cseg + i];
        unsigned short h = f2bf(f);
        dh[i] = h;
        dl[i] = f2bf(f - bf2f(h));
    }
}

// ---------------------------------------------------------------------------
// Kernel B: 16 penalty cell ids per keypoint.
// ---------------------------------------------------------------------------
__global__ __launch_bounds__(256) void mask_kernel(
    const float* __restrict__ kp1, const float* __restrict__ homo,
    int* __restrict__ mask_ids)
{
    int g = blockIdx.x * blockDim.x + threadIdx.x;
    if (g >= NB * NN) return;
    int b = g >> 10;
    float x = kp1[g * 2], y = kp1[g * 2 + 1];
    const float* H = homo + b * 9;
    int c4[4];
    nearest4(x, y, c4);
    int out[16];
    #pragma unroll
    for (int k = 0; k < 4; ++k) {
        int id = c4[k];
        float cx = ((float)(id & 63) + 0.5f) * 8.0f;
        float cy = ((float)(id >> 6) + 0.5f) * 8.0f;
        float q0 = H[0] * cx + H[1] * cy + H[2];
        float q1 = H[3] * cx + H[4] * cy + H[5];
        float q2 = H[6] * cx + H[7] * cy + H[8];
        float iz = 1.0f / (q2 + 1e-8f);
        nearest4(q0 * iz, q1 * iz, out + 4 * k);
    }
    #pragma unroll
    for (int k = 0; k < 16; ++k) mask_ids[(size_t)g * 16 + k] = out[k];
}

// ---------------------------------------------------------------------------
// Fused sim+top8, MFMA edition. Same grid split as round 3:
//   blocks [0,1024):    FOS  (A=k, B=d2, ncols=4096, 4 col-blocks)
//   blocks [1024,1536): SOS-A (A=k, B=k, ncols=1024, 2 col-blocks)
//   blocks [1536,2048): SOS-B (A=w, B=w, ncols=1024, 2 col-blocks)
// sim = 2 - 2*(A.Bt) via 3-term bf16 split: hi*hi + hi*lo + lo*hi.
// 16x16x32 MFMA: A[l&15][8*(l>>4)+e], B[8*(l>>4)+e][l&15],
// D: col=lane&15, row=(lane>>4)*4+reg (m89-verified).
// A-fragments (16 rows x K=128, hi+lo = 32 VGPR) register-resident.
// ---------------------------------------------------------------------------
__global__ __launch_bounds__(256, 4) void simtop_fused(
    const unsigned short* __restrict__ khi, const unsigned short* __restrict__ klo,
    const unsigned short* __restrict__ whi, const unsigned short* __restrict__ wlo,
    const unsigned short* __restrict__ d2hi, const unsigned short* __restrict__ d2lo,
    const float* __restrict__ kp1, const float* __restrict__ w_kp1,
    const int* __restrict__ mask_ids,
    float* __restrict__ fosP, float* __restrict__ sosAP, float* __restrict__ sosBP)
{
    __shared__ float sChunk[16][257];    // sim chunk; aliased as merge buffer
    __shared__ int   sMask[16][16];
    __shared__ float sCx[256], sCy[256];
    __shared__ float sRx[16], sRy[16];

    int tid = threadIdx.x;
    int bid = blockIdx.x;

    int mode, cs, rg, b, nchunk, colbase, outStride;
    const unsigned short *AH, *AL, *BH, *BL;
    const float* coords = nullptr;
    float* outP;
    if (bid < 1024) {
        mode = 0; cs = bid & 3; rg = (bid >> 2) & 63; b = bid >> 8;
        nchunk = 4; colbase = cs * 1024;
        AH = khi + (size_t)b * NN * NCCH;  AL = klo + (size_t)b * NN * NCCH;
        BH = d2hi + (size_t)b * NHW * NCCH; BL = d2lo + (size_t)b * NHW * NCCH;
        outP = fosP; outStride = 32;
    } else if (bid < 1536) {
        int id = bid - 1024;
        mode = 1; cs = id & 1; rg = (id >> 1) & 63; b = id >> 7;
        nchunk = 2; colbase = cs * 512;
        AH = khi + (size_t)b * NN * NCCH;  AL = klo + (size_t)b * NN * NCCH;
        BH = AH; BL = AL;
        coords = kp1; outP = sosAP; outStride = 16;
    } else {
        int id = bid - 1536;
        mode = 2; cs = id & 1; rg = (id >> 1) & 63; b = id >> 7;
        nchunk = 2; colbase = cs * 512;
        AH = whi + (size_t)b * NN * NCCH;  AL = wlo + (size_t)b * NN * NCCH;
        BH = AH; BL = AL;
        coords = w_kp1; outP = sosBP; outStride = 16;
    }
    int row0 = rg * 16;

    int lane = tid & 63, wg = tid >> 6;
    int lrow = lane & 15, lgrp = lane >> 4;
    int srow = tid & 15, sgrp = tid >> 4;

    // A fragments: row = row0 + (l&15), k = s*32 + (l>>4)*8 + e
    short8v ahi[4], alo[4];
    {
        const unsigned short* aH = AH + (size_t)(row0 + lrow) * NCCH + lgrp * 8;
        const unsigned short* aL = AL + (size_t)(row0 + lrow) * NCCH + lgrp * 8;
        #pragma unroll
        for (int s = 0; s < 4; ++s) {
            ahi[s] = *(const short8v*)(aH + s * 32);
            alo[s] = *(const short8v*)(aL + s * 32);
        }
    }

    if (mode == 0) {
        sMask[tid >> 4][tid & 15] =
            mask_ids[((size_t)b * NN + row0 + (tid >> 4)) * 16 + (tid & 15)];
    } else if (tid < 16) {
        sRx[tid] = coords[((size_t)b * NN + row0 + tid) * 2];
        sRy[tid] = coords[((size_t)b * NN + row0 + tid) * 2 + 1];
    }

    float loc[8];
    #pragma unroll
    for (int k = 0; k < 8; ++k) loc[k] = 1e30f;

    for (int ch = 0; ch < nchunk; ++ch) {
        int cglob = colbase + ch * 256;
        __syncthreads();                 // sChunk free from previous selection

        int colq = cglob + wg * 64;      // this wave's 64-col slice
        #pragma unroll
        for (int nt = 0; nt < 4; ++nt) {
            const unsigned short* bH = BH + (size_t)(colq + nt * 16 + lrow) * NCCH + lgrp * 8;
            const unsigned short* bL = BL + (size_t)(colq + nt * 16 + lrow) * NCCH + lgrp * 8;
            f32x4 acc = {0.f, 0.f, 0.f, 0.f};
            #pragma unroll
            for (int s = 0; s < 4; ++s) {
                short8v bhv = *(const short8v*)(bH + s * 32);
                short8v blv = *(const short8v*)(bL + s * 32);
                acc = __builtin_amdgcn_mfma_f32_16x16x32_bf16(ahi[s], bhv, acc, 0, 0, 0);
                acc = __builtin_amdgcn_mfma_f32_16x16x32_bf16(ahi[s], blv, acc, 0, 0, 0);
                acc = __builtin_amdgcn_mfma_f32_16x16x32_bf16(alo[s], bhv, acc, 0, 0, 0);
            }
            #pragma unroll
            for (int r = 0; r < 4; ++r)
                sChunk[lgrp * 4 + r][wg * 64 + nt * 16 + lrow] = 2.0f - 2.0f * acc[r];
        }
        __syncthreads();

        if (mode == 0) {
            int r = tid >> 4, k = tid & 15;
            int id = sMask[r][k] - cglob;
            if (id >= 0 && id < 256) atomicAdd(&sChunk[r][id], 5.0f);
        } else {
            sCx[tid] = coords[((size_t)b * NN + cglob + tid) * 2];
            sCy[tid] = coords[((size_t)b * NN + cglob + tid) * 2 + 1];
        }
        __syncthreads();

        float rx = 0.f, ry = 0.f;
        if (mode != 0) { rx = sRx[srow]; ry = sRy[srow]; }
        #pragma unroll
        for (int j = 0; j < 16; ++j) {
            int cl = sgrp * 16 + j;      // consecutive-16 ownership: 2-way banks
            float v = sChunk[srow][cl];
            if (mode != 0) {
                float dx = rx - sCx[cl], dy = ry - sCy[cl];
                if (dx * dx + dy * dy <= RADIUS2) v += 5.0f;
            }
            if (v < loc[7]) {
                loc[7] = v;
                #pragma unroll
                for (int p = 7; p > 0; --p) {
                    if (loc[p - 1] > loc[p]) {
                        float t = loc[p - 1]; loc[p - 1] = loc[p]; loc[p] = t;
                    }
                }
            }
        }
    }

    // parallel tree merge of the 16 per-thread sorted lists per row
    __syncthreads();
    float* mg = &sChunk[0][0];           // [16][130] alias
    #pragma unroll
    for (int k = 0; k < 8; ++k) mg[srow * 130 + sgrp * 8 + k] = loc[k];
    __syncthreads();
    #pragma unroll
    for (int step = 1; step < 16; step <<= 1) {
        if ((sgrp & (2 * step - 1)) == 0) {
            float a[8], bb[8], o[8];
            #pragma unroll
            for (int k = 0; k < 8; ++k) {
                a[k]  = mg[srow * 130 + sgrp * 8 + k];
                bb[k] = mg[srow * 130 + (sgrp + step) * 8 + k];
            }
            merge8(a, bb, o);
            #pragma unroll
            for (int k = 0; k < 8; ++k) mg[srow * 130 + sgrp * 8 + k] = o[k];
        }
        __syncthreads();
    }
    if (tid < 16) {
        size_t row = (size_t)b * NN + row0 + tid;
        #pragma unroll
        for (int k = 0; k < 8; ++k)
            outP[row * outStride + cs * 8 + k] = mg[tid * 130 + k];
    }
}

// ---------------------------------------------------------------------------
// Per-row finalize: merge partial top-8 lists, hinge (FOS) and sqrt-diff (SOS)
// ---------------------------------------------------------------------------
__global__ __launch_bounds__(256) void frow_kernel(
    const float* __restrict__ fosP, const float* __restrict__ sosAP,
    const float* __restrict__ sosBP, const float* __restrict__ pos_sim,
    float* __restrict__ frow, float* __restrict__ srow)
{
    int row = blockIdx.x * 256 + threadIdx.x;
    if (row >= NB * NN) return;

    float l0[8], l1[8], l2[8], l3[8], t0[8], t1[8], m[8];
    const float4* fp = (const float4*)(fosP + (size_t)row * 32);
    float4 q;
    q = fp[0]; l0[0]=q.x; l0[1]=q.y; l0[2]=q.z; l0[3]=q.w;
    q = fp[1]; l0[4]=q.x; l0[5]=q.y; l0[6]=q.z; l0[7]=q.w;
    q = fp[2]; l1[0]=q.x; l1[1]=q.y; l1[2]=q.z; l1[3]=q.w;
    q = fp[3]; l1[4]=q.x; l1[5]=q.y; l1[6]=q.z; l1[7]=q.w;
    q = fp[4]; l2[0]=q.x; l2[1]=q.y; l2[2]=q.z; l2[3]=q.w;
    q = fp[5]; l2[4]=q.x; l2[5]=q.y; l2[6]=q.z; l2[7]=q.w;
    q = fp[6]; l3[0]=q.x; l3[1]=q.y; l3[2]=q.z; l3[3]=q.w;
    q = fp[7]; l3[4]=q.x; l3[5]=q.y; l3[6]=q.z; l3[7]=q.w;
    merge8(l0, l1, t0); merge8(l2, l3, t1); merge8(t0, t1, m);

    float p = pos_sim[row], fs = 0.f;
    #pragma unroll
    for (int k = 0; k < 8; ++k) {
        float h = fmaxf(p - m[k] + 1.0f, 0.f);
        fs += h * h;
    }

    const float4* ap = (const float4*)(sosAP + (size_t)row * 16);
    q = ap[0]; l0[0]=q.x; l0[1]=q.y; l0[2]=q.z; l0[3]=q.w;
    q = ap[1]; l0[4]=q.x; l0[5]=q.y; l0[6]=q.z; l0[7]=q.w;
    q = ap[2]; l1[0]=q.x; l1[1]=q.y; l1[2]=q.z; l1[3]=q.w;
    q = ap[3]; l1[4]=q.x; l1[5]=q.y; l1[6]=q.z; l1[7]=q.w;
    merge8(l0, l1, t0);
    const float4* bp = (const float4*)(sosBP + (size_t)row * 16);
    q = bp[0]; l2[0]=q.x; l2[1]=q.y; l2[2]=q.z; l2[3]=q.w;
    q = bp[1]; l2[4]=q.x; l2[5]=q.y; l2[6]=q.z; l2[7]=q.w;
    q = bp[2]; l3[0]=q.x; l3[1]=q.y; l3[2]=q.z; l3[3]=q.w;
    q = bp[3]; l3[4]=q.x; l3[5]=q.y; l3[6]=q.z; l3[7]=q.w;
    merge8(l2, l3, t1);

    float acc = 0.f;
    #pragma unroll
    for (int k = 0; k < 8; ++k) {
        float d = t0[k] - t1[k];
        acc += d * d;
    }
    frow[row] = fs;
    srow[row] = sqrtf(acc);
}

__global__ __launch_bounds__(256) void freduce_kernel(
    const float* __restrict__ frow, const float* __restrict__ srow,
    float* __restrict__ outp)
{
    __shared__ float sf[256], ss[256];
    int t = threadIdx.x;
    float f = 0.f, s = 0.f;
    for (int i = t; i < NB * NN; i += 256) { f += frow[i]; s += srow[i]; }
    sf[t] = f; ss[t] = s;
    __syncthreads();
    for (int o = 128; o > 0; o >>= 1) {
        if (t < o) { sf[t] += sf[t + o]; ss[t] += ss[t + o]; }
        __syncthreads();
    }
    if (t == 0)
        outp[0] = sf[0] / (float)(NB * NN * 8) + ss[0] / (float)(NB * NN);
}

extern "C" void kernel_launch(void* const* d_in, const int* in_sizes, int n_in,
                              void* d_out, int out_size, void* d_ws, size_t ws_size,
                              hipStream_t stream) {
    const float* kp1      = (const float*)d_in[0];
    const float* w_kp1    = (const float*)d_in[1];
    const float* kp1_desc = (const float*)d_in[2];
    const float* desc2    = (const float*)d_in[3];
    const float* homo     = (const float*)d_in[4];
    float* outp = (float*)d_out;

    char* ws = (char*)d_ws;
    size_t o = 0;
    unsigned short* khi  = (unsigned short*)(ws + o); o += (size_t)NB * NN * NCCH * 2;
    unsigned short* klo  = (unsigned short*)(ws + o); o += (size_t)NB * NN * NCCH * 2;
    unsigned short* whi  = (unsigned short*)(ws + o); o += (size_t)NB * NN * NCCH * 2;
    unsigned short* wlo  = (unsigned short*)(ws + o); o += (size_t)NB * NN * NCCH * 2;
    unsigned short* d2hi = (unsigned short*)(ws + o); o += (size_t)NB * NHW * NCCH * 2;
    unsigned short* d2lo = (unsigned short*)(ws + o); o += (size_t)NB * NHW * NCCH * 2;
    float* pos_sim = (float*)(ws + o); o += (size_t)NB * NN * 4;
    float* fosP    = (float*)(ws + o); o += (size_t)NB * NN * 32 * 4;
    float* sosAP   = (float*)(ws + o); o += (size_t)NB * NN * 16 * 4;
    float* sosBP   = (float*)(ws + o); o += (size_t)NB * NN * 16 * 4;
    float* frow    = (float*)(ws + o); o += (size_t)NB * NN * 4;
    float* srow    = (float*)(ws + o); o += (size_t)NB * NN * 4;
    int*   mask_id = (int*)(ws + o);   o += (size_t)NB * NN * 16 * 4;

    sample_kernel<<<NB * NN / 4, 256, 0, stream>>>(kp1, w_kp1, kp1_desc, desc2,
                                                   khi, klo, whi, wlo, pos_sim);
    d2split_kernel<<<NB * 64, 256, 0, stream>>>(desc2, d2hi, d2lo);
    mask_kernel<<<NB * NN / 256, 256, 0, stream>>>(kp1, homo, mask_id);
    simtop_fused<<<2048, 256, 0, stream>>>(khi, klo, whi, wlo, d2hi, d2lo,
                                           kp1, w_kp1, mask_id,
                                           fosP, sosAP, sosBP);
    frow_kernel<<<16, 256, 0, stream>>>(fosP, sosAP, sosBP, pos_sim, frow, srow);
    freduce_kernel<<<1, 256, 0, stream>>>(frow, srow, outp);
}

// Round 5
// 199.748 us; speedup vs baseline: 3.3280x; 1.0605x over previous
//
#include <hip/hip_runtime.h>

#define NB 4
#define NN 1024
#define NCCH 128
#define NH 64
#define NW 64
#define NHW 4096

// (8*sqrt(2)+0.1)^2
constexpr float RADIUS2 = 130.27274173013714f;

typedef __attribute__((ext_vector_type(8))) short short8v;   // 8 bf16 = 4 VGPR
typedef __attribute__((ext_vector_type(4))) float f32x4;

__device__ __forceinline__ unsigned short f2bf(float f) {   // RNE f32->bf16
    unsigned u = __float_as_uint(f);
    unsigned r = u + 0x7FFFu + ((u >> 16) & 1u);
    return (unsigned short)(r >> 16);
}
__device__ __forceinline__ float bf2f(unsigned short h) {
    return __uint_as_float(((unsigned)h) << 16);
}

// ---------------------------------------------------------------------------
// bitonic partial merge: two ascending sorted-8 lists -> smallest 8 ascending
// ---------------------------------------------------------------------------
__device__ __forceinline__ void bsort8(float* v) {
    #pragma unroll
    for (int d = 4; d >= 1; d >>= 1) {
        #pragma unroll
        for (int i = 0; i < 8; ++i) {
            if ((i & d) == 0) {
                float x = v[i], y = v[i + d];
                v[i] = fminf(x, y);
                v[i + d] = fmaxf(x, y);
            }
        }
    }
}
__device__ __forceinline__ void merge8(const float* a, const float* b, float* o) {
    #pragma unroll
    for (int k = 0; k < 8; ++k) o[k] = fminf(a[k], b[7 - k]);
    bsort8(o);
}

// ---------------------------------------------------------------------------
// 4 nearest grid-cell centers; strict '<' + increasing linear id replicates
// jax.lax.top_k tie-breaking.
// ---------------------------------------------------------------------------
__device__ __forceinline__ void nearest4(float x, float y, int out_ids[4]) {
    float u = x * 0.125f - 0.5f;
    float v = y * 0.125f - 0.5f;
    u = fminf(fmaxf(u, -1e6f), 1e6f);
    v = fminf(fmaxf(v, -1e6f), 1e6f);
    int iu = (int)floorf(u);
    int iv = (int)floorf(v);
    int xlo = min(max(iu - 2, 0), 60);
    int xhi = max(min(iu + 3, 63), 3);
    int ylo = min(max(iv - 2, 0), 60);
    int yhi = max(min(iv + 3, 63), 3);
    float bd0 = 1e30f, bd1 = 1e30f, bd2 = 1e30f, bd3 = 1e30f;
    int bi0 = 0, bi1 = 0, bi2 = 0, bi3 = 0;
    for (int yy = ylo; yy <= yhi; ++yy) {
        float dy = y - ((float)yy + 0.5f) * 8.0f;
        float dy2 = dy * dy;
        for (int xx = xlo; xx <= xhi; ++xx) {
            float dx = x - ((float)xx + 0.5f) * 8.0f;
            float d = dx * dx + dy2;
            int id = (yy << 6) | xx;
            if (d < bd3) {
                if (d < bd2) {
                    bd3 = bd2; bi3 = bi2;
                    if (d < bd1) {
                        bd2 = bd1; bi2 = bi1;
                        if (d < bd0) { bd1 = bd0; bi1 = bi0; bd0 = d; bi0 = id; }
                        else         { bd1 = d;  bi1 = id; }
                    } else { bd2 = d; bi2 = id; }
                } else { bd3 = d; bi3 = id; }
            }
        }
    }
    out_ids[0] = bi0; out_ids[1] = bi1; out_ids[2] = bi2; out_ids[3] = bi3;
}

// ---------------------------------------------------------------------------
// d2split v2: desc2 [B][C][HW] -> bf16 hi/lo in [B][HW][C]; optionally also an
// exact f32 transposed copy d2T [B][HW][C] (for coalesced sampling).
// Grid: NB * 64(hw tiles of 64) * 4(c tiles of 32) = 1024 blocks.
// ---------------------------------------------------------------------------
__global__ __launch_bounds__(256) void d2split_kernel(
    const float* __restrict__ desc2,
    unsigned short* __restrict__ d2hi, unsigned short* __restrict__ d2lo,
    float* __restrict__ d2T, int use_t)
{
    __shared__ float sT[64][33];
    int bid = blockIdx.x;
    int b = bid >> 8;
    int rem = bid & 255;
    int hw0 = (rem >> 2) * 64;
    int c0 = (rem & 3) * 32;
    int t = threadIdx.x;

    {
        int lane = t & 63, cg = t >> 6;
        const float* src = desc2 + (size_t)b * NCCH * NHW + hw0 + lane;
        #pragma unroll
        for (int i = 0; i < 8; ++i) {
            int cl = cg * 8 + i;
            sT[lane][cl] = src[(size_t)(c0 + cl) * NHW];
        }
    }
    __syncthreads();
    {
        int hw = t >> 2, q = t & 3;
        size_t base = ((size_t)b * NHW + hw0 + hw) * NCCH + c0 + q * 8;
        unsigned short hb[8], lb[8];
        float fb[8];
        #pragma unroll
        for (int i = 0; i < 8; ++i) {
            float f = sT[hw][q * 8 + i];
            unsigned short h = f2bf(f);
            hb[i] = h;
            lb[i] = f2bf(f - bf2f(h));
            fb[i] = f;
        }
        *(short8v*)(d2hi + base) = *(short8v*)hb;
        *(short8v*)(d2lo + base) = *(short8v*)lb;
        if (use_t) {
            *(float4*)(d2T + base) = *(float4*)&fb[0];
            *(float4*)(d2T + base + 4) = *(float4*)&fb[4];
        }
    }
}

// ---------------------------------------------------------------------------
// sample+mask fused. blocks [0,1024): wave-per-keypoint bilinear sample,
// L2-normalize, positive_sim, bf16 hi/lo splits of kp1_desc and w_desc.
// blocks [1024,1040): penalty mask ids (thread-per-keypoint).
// ---------------------------------------------------------------------------
__global__ __launch_bounds__(256) void sample_mask_kernel(
    const float* __restrict__ kp1, const float* __restrict__ w_kp1,
    const float* __restrict__ kp1_desc, const float* __restrict__ desc2,
    const float* __restrict__ d2T, int use_t,
    const float* __restrict__ homo,
    unsigned short* __restrict__ khi, unsigned short* __restrict__ klo,
    unsigned short* __restrict__ whi, unsigned short* __restrict__ wlo,
    float* __restrict__ pos_sim, int* __restrict__ mask_ids)
{
    int bid = blockIdx.x;
    if (bid >= 1024) {                 // ---- mask path ----
        int g = (bid - 1024) * 256 + threadIdx.x;
        if (g >= NB * NN) return;
        int b = g >> 10;
        float x = kp1[g * 2], y = kp1[g * 2 + 1];
        const float* H = homo + b * 9;
        int c4[4];
        nearest4(x, y, c4);
        int out[16];
        #pragma unroll
        for (int k = 0; k < 4; ++k) {
            int id = c4[k];
            float cx = ((float)(id & 63) + 0.5f) * 8.0f;
            float cy = ((float)(id >> 6) + 0.5f) * 8.0f;
            float q0 = H[0] * cx + H[1] * cy + H[2];
            float q1 = H[3] * cx + H[4] * cy + H[5];
            float q2 = H[6] * cx + H[7] * cy + H[8];
            float iz = 1.0f / (q2 + 1e-8f);
            nearest4(q0 * iz, q1 * iz, out + 4 * k);
        }
        #pragma unroll
        for (int k = 0; k < 16; ++k) mask_ids[(size_t)g * 16 + k] = out[k];
        return;
    }

    // ---- sample path: one wave per keypoint ----
    int lane = threadIdx.x & 63;
    int wid = bid * 4 + (threadIdx.x >> 6);
    int b = wid >> 10;

    float px = w_kp1[wid * 2 + 0], py = w_kp1[wid * 2 + 1];
    float fx = px * 0.125f - 0.5f, fy = py * 0.125f - 0.5f;
    float fx0 = floorf(fx), fy0 = floorf(fy);
    float wx = fx - fx0, wy = fy - fy0;
    int x0 = min(max((int)fx0, 0), NW - 1);
    int x1 = min(x0 + 1, NW - 1);
    int y0 = min(max((int)fy0, 0), NH - 1);
    int y1 = min(y0 + 1, NH - 1);
    float w00 = (1.f - wx) * (1.f - wy), w01 = wx * (1.f - wy);
    float w10 = (1.f - wx) * wy,         w11 = wx * wy;
    int i00 = y0 * NW + x0, i01 = y0 * NW + x1;
    int i10 = y1 * NW + x0, i11 = y1 * NW + x1;

    float o0, o1;
    if (use_t) {                       // coalesced: [HW][C] rows
        const float* base = d2T + (size_t)b * NHW * NCCH;
        const float* r00 = base + (size_t)i00 * NCCH;
        const float* r01 = base + (size_t)i01 * NCCH;
        const float* r10 = base + (size_t)i10 * NCCH;
        const float* r11 = base + (size_t)i11 * NCCH;
        o0 = w00 * r00[lane] + w01 * r01[lane] + w10 * r10[lane] + w11 * r11[lane];
        o1 = w00 * r00[lane + 64] + w01 * r01[lane + 64]
           + w10 * r10[lane + 64] + w11 * r11[lane + 64];
    } else {                           // fallback: original [C][HW] gather
        const float* d2 = desc2 + (size_t)b * NCCH * NHW;
        const float* p0 = d2 + (size_t)lane * NHW;
        const float* p1 = d2 + (size_t)(lane + 64) * NHW;
        o0 = w00 * p0[i00] + w01 * p0[i01] + w10 * p0[i10] + w11 * p0[i11];
        o1 = w00 * p1[i00] + w01 * p1[i01] + w10 * p1[i10] + w11 * p1[i11];
    }
    float nrm = o0 * o0 + o1 * o1;
    #pragma unroll
    for (int off = 32; off > 0; off >>= 1) nrm += __shfl_xor(nrm, off, 64);
    float inv = 1.0f / (sqrtf(nrm) + 1e-8f);
    o0 *= inv; o1 *= inv;

    float a0 = kp1_desc[(size_t)wid * NCCH + lane];
    float a1 = kp1_desc[(size_t)wid * NCCH + lane + 64];
    float dot = a0 * o0 + a1 * o1;
    #pragma unroll
    for (int off = 32; off > 0; off >>= 1) dot += __shfl_xor(dot, off, 64);

    size_t base = (size_t)wid * NCCH;
    unsigned short h;
    h = f2bf(a0); khi[base + lane] = h;      klo[base + lane] = f2bf(a0 - bf2f(h));
    h = f2bf(a1); khi[base + lane + 64] = h; klo[base + lane + 64] = f2bf(a1 - bf2f(h));
    h = f2bf(o0); whi[base + lane] = h;      wlo[base + lane] = f2bf(o0 - bf2f(h));
    h = f2bf(o1); whi[base + lane + 64] = h; wlo[base + lane + 64] = f2bf(o1 - bf2f(h));
    if (lane == 0) pos_sim[wid] = 2.0f - 2.0f * dot;
}

// ---------------------------------------------------------------------------
// Fused sim+top8, MFMA, 32 rows/block (2 register-resident A row-tiles per
// wave -> each B fragment feeds 2 accumulators; nt-tiles processed in pairs
// -> 4 independent MFMA chains).
//   blocks [0,512):    FOS  (A=k, B=d2, 4 col-slices of 1024)
//   blocks [512,768):  SOS-A (A=B=k, 2 col-slices of 512)
//   blocks [768,1024): SOS-B (A=B=w, 2 col-slices of 512)
// sim = 2 - 2*(A.Bt) via 3-term bf16 split: hi*hi + hi*lo + lo*hi.
// 16x16x32 layouts: A[l&15][8*(l>>4)+e], B[8*(l>>4)+e][l&15],
// D: col=lane&15, row=(lane>>4)*4+reg (m89-verified).
// ---------------------------------------------------------------------------
__global__ __launch_bounds__(256, 4) void simtop_fused(
    const unsigned short* __restrict__ khi, const unsigned short* __restrict__ klo,
    const unsigned short* __restrict__ whi, const unsigned short* __restrict__ wlo,
    const unsigned short* __restrict__ d2hi, const unsigned short* __restrict__ d2lo,
    const float* __restrict__ kp1, const float* __restrict__ w_kp1,
    const int* __restrict__ mask_ids,
    float* __restrict__ fosP, float* __restrict__ sosAP, float* __restrict__ sosBP)
{
    __shared__ float sChunk[32][257];    // 32.9 KB; aliased as merge buffer
    __shared__ int   sMask[32][16];
    __shared__ float sCx[256], sCy[256];
    __shared__ float sRx[32], sRy[32];

    int tid = threadIdx.x;
    int bid = blockIdx.x;

    int mode, cs, rg, b, nchunk, colbase, outStride;
    const unsigned short *AH, *AL, *BH, *BL;
    const float* coords = nullptr;
    float* outP;
    if (bid < 512) {
        mode = 0; b = bid >> 7; int rem = bid & 127;
        cs = rem & 3; rg = rem >> 2;
        nchunk = 4; colbase = cs * 1024;
        AH = khi + (size_t)b * NN * NCCH;  AL = klo + (size_t)b * NN * NCCH;
        BH = d2hi + (size_t)b * NHW * NCCH; BL = d2lo + (size_t)b * NHW * NCCH;
        outP = fosP; outStride = 32;
    } else if (bid < 768) {
        int id = bid - 512;
        mode = 1; b = id >> 6; int rem = id & 63;
        cs = rem & 1; rg = rem >> 1;
        nchunk = 2; colbase = cs * 512;
        AH = khi + (size_t)b * NN * NCCH;  AL = klo + (size_t)b * NN * NCCH;
        BH = AH; BL = AL;
        coords = kp1; outP = sosAP; outStride = 16;
    } else {
        int id = bid - 768;
        mode = 2; b = id >> 6; int rem = id & 63;
        cs = rem & 1; rg = rem >> 1;
        nchunk = 2; colbase = cs * 512;
        AH = whi + (size_t)b * NN * NCCH;  AL = wlo + (size_t)b * NN * NCCH;
        BH = AH; BL = AL;
        coords = w_kp1; outP = sosBP; outStride = 16;
    }
    int row0 = rg * 32;

    int lane = tid & 63, wg = tid >> 6;
    int lrow = lane & 15, lgrp = lane >> 4;
    int srow = tid & 31, sgrp = tid >> 5;     // selection: 8 threads/row, 32 cols each

    // A fragments: 2 row-tiles x 4 k-steps, hi+lo (64 VGPR)
    short8v ahi[2][4], alo[2][4];
    #pragma unroll
    for (int rt = 0; rt < 2; ++rt) {
        const unsigned short* aH = AH + (size_t)(row0 + rt * 16 + lrow) * NCCH + lgrp * 8;
        const unsigned short* aL = AL + (size_t)(row0 + rt * 16 + lrow) * NCCH + lgrp * 8;
        #pragma unroll
        for (int s = 0; s < 4; ++s) {
            ahi[rt][s] = *(const short8v*)(aH + s * 32);
            alo[rt][s] = *(const short8v*)(aL + s * 32);
        }
    }

    if (mode == 0) {
        for (int e = tid; e < 512; e += 256)
            sMask[e >> 4][e & 15] =
                mask_ids[((size_t)b * NN + row0 + (e >> 4)) * 16 + (e & 15)];
    } else if (tid < 32) {
        sRx[tid] = coords[((size_t)b * NN + row0 + tid) * 2];
        sRy[tid] = coords[((size_t)b * NN + row0 + tid) * 2 + 1];
    }

    float loc[8];
    #pragma unroll
    for (int k = 0; k < 8; ++k) loc[k] = 1e30f;

    for (int ch = 0; ch < nchunk; ++ch) {
        int cglob = colbase + ch * 256;
        __syncthreads();                 // sChunk free from previous selection

        int colq = cglob + wg * 64;      // this wave's 64-col slice
        #pragma unroll
        for (int np = 0; np < 2; ++np) {
            const unsigned short* b0H = BH + (size_t)(colq + (np * 2 + 0) * 16 + lrow) * NCCH + lgrp * 8;
            const unsigned short* b0L = BL + (size_t)(colq + (np * 2 + 0) * 16 + lrow) * NCCH + lgrp * 8;
            const unsigned short* b1H = BH + (size_t)(colq + (np * 2 + 1) * 16 + lrow) * NCCH + lgrp * 8;
            const unsigned short* b1L = BL + (size_t)(colq + (np * 2 + 1) * 16 + lrow) * NCCH + lgrp * 8;
            f32x4 a00 = {0.f, 0.f, 0.f, 0.f}, a01 = {0.f, 0.f, 0.f, 0.f};
            f32x4 a10 = {0.f, 0.f, 0.f, 0.f}, a11 = {0.f, 0.f, 0.f, 0.f};
            #pragma unroll
            for (int s = 0; s < 4; ++s) {
                short8v bh0 = *(const short8v*)(b0H + s * 32);
                short8v bl0 = *(const short8v*)(b0L + s * 32);
                short8v bh1 = *(const short8v*)(b1H + s * 32);
                short8v bl1 = *(const short8v*)(b1L + s * 32);
                // 4 independent chains; per-acc order (hh,hl,lh) == round-4 numerics
                a00 = __builtin_amdgcn_mfma_f32_16x16x32_bf16(ahi[0][s], bh0, a00, 0, 0, 0);
                a10 = __builtin_amdgcn_mfma_f32_16x16x32_bf16(ahi[1][s], bh0, a10, 0, 0, 0);
                a01 = __builtin_amdgcn_mfma_f32_16x16x32_bf16(ahi[0][s], bh1, a01, 0, 0, 0);
                a11 = __builtin_amdgcn_mfma_f32_16x16x32_bf16(ahi[1][s], bh1, a11, 0, 0, 0);
                a00 = __builtin_amdgcn_mfma_f32_16x16x32_bf16(ahi[0][s], bl0, a00, 0, 0, 0);
                a10 = __builtin_amdgcn_mfma_f32_16x16x32_bf16(ahi[1][s], bl0, a10, 0, 0, 0);
                a01 = __builtin_amdgcn_mfma_f32_16x16x32_bf16(ahi[0][s], bl1, a01, 0, 0, 0);
                a11 = __builtin_amdgcn_mfma_f32_16x16x32_bf16(ahi[1][s], bl1, a11, 0, 0, 0);
                a00 = __builtin_amdgcn_mfma_f32_16x16x32_bf16(alo[0][s], bh0, a00, 0, 0, 0);
                a10 = __builtin_amdgcn_mfma_f32_16x16x32_bf16(alo[1][s], bh0, a10, 0, 0, 0);
                a01 = __builtin_amdgcn_mfma_f32_16x16x32_bf16(alo[0][s], bh1, a01, 0, 0, 0);
                a11 = __builtin_amdgcn_mfma_f32_16x16x32_bf16(alo[1][s], bh1, a11, 0, 0, 0);
            }
            #pragma unroll
            for (int r = 0; r < 4; ++r) {
                sChunk[lgrp * 4 + r][wg * 64 + (np * 2 + 0) * 16 + lrow]      = 2.0f - 2.0f * a00[r];
                sChunk[16 + lgrp * 4 + r][wg * 64 + (np * 2 + 0) * 16 + lrow] = 2.0f - 2.0f * a10[r];
                sChunk[lgrp * 4 + r][wg * 64 + (np * 2 + 1) * 16 + lrow]      = 2.0f - 2.0f * a01[r];
                sChunk[16 + lgrp * 4 + r][wg * 64 + (np * 2 + 1) * 16 + lrow] = 2.0f - 2.0f * a11[r];
            }
        }
        __syncthreads();

        if (mode == 0) {
            for (int e = tid; e < 512; e += 256) {
                int r = e >> 4;
                int id = sMask[r][e & 15] - cglob;
                if (id >= 0 && id < 256) atomicAdd(&sChunk[r][id], 5.0f);
            }
        } else {
            sCx[tid] = coords[((size_t)b * NN + cglob + tid) * 2];
            sCy[tid] = coords[((size_t)b * NN + cglob + tid) * 2 + 1];
        }
        __syncthreads();

        float rx = 0.f, ry = 0.f;
        if (mode != 0) { rx = sRx[srow]; ry = sRy[srow]; }
        #pragma unroll
        for (int j = 0; j < 32; ++j) {
            int cl = sgrp * 32 + j;
            float v = sChunk[srow][cl];
            if (mode != 0) {
                float dx = rx - sCx[cl], dy = ry - sCy[cl];
                if (dx * dx + dy * dy <= RADIUS2) v += 5.0f;
            }
            if (v < loc[7]) {
                loc[7] = v;
                #pragma unroll
                for (int p = 7; p > 0; --p) {
                    if (loc[p - 1] > loc[p]) {
                        float t = loc[p - 1]; loc[p - 1] = loc[p]; loc[p] = t;
                    }
                }
            }
        }
    }

    // parallel tree merge of the 8 per-thread sorted lists per row
    __syncthreads();
    float* mg = &sChunk[0][0];           // [32][67] alias (2144 < 8224 floats)
    #pragma unroll
    for (int k = 0; k < 8; ++k) mg[srow * 67 + sgrp * 8 + k] = loc[k];
    __syncthreads();
    #pragma unroll
    for (int step = 1; step < 8; step <<= 1) {
        if ((sgrp & (2 * step - 1)) == 0) {
            float a[8], bb[8], o[8];
            #pragma unroll
            for (int k = 0; k < 8; ++k) {
                a[k]  = mg[srow * 67 + sgrp * 8 + k];
                bb[k] = mg[srow * 67 + (sgrp + step) * 8 + k];
            }
            merge8(a, bb, o);
            #pragma unroll
            for (int k = 0; k < 8; ++k) mg[srow * 67 + sgrp * 8 + k] = o[k];
        }
        __syncthreads();
    }
    if (tid < 32) {
        size_t row = (size_t)b * NN + row0 + tid;
        #pragma unroll
        for (int k = 0; k < 8; ++k)
            outP[row * outStride + cs * 8 + k] = mg[tid * 67 + k];
    }
}

// ---------------------------------------------------------------------------
// Per-row finalize: merge partial top-8 lists, hinge (FOS) and sqrt-diff (SOS)
// ---------------------------------------------------------------------------
__global__ __launch_bounds__(256) void frow_kernel(
    const float* __restrict__ fosP, const float* __restrict__ sosAP,
    const float* __restrict__ sosBP, const float* __restrict__ pos_sim,
    float* __restrict__ frow, float* __restrict__ srow)
{
    int row = blockIdx.x * 256 + threadIdx.x;
    if (row >= NB * NN) return;

    float l0[8], l1[8], l2[8], l3[8], t0[8], t1[8], m[8];
    const float4* fp = (const float4*)(fosP + (size_t)row * 32);
    float4 q;
    q = fp[0]; l0[0]=q.x; l0[1]=q.y; l0[2]=q.z; l0[3]=q.w;
    q = fp[1]; l0[4]=q.x; l0[5]=q.y; l0[6]=q.z; l0[7]=q.w;
    q = fp[2]; l1[0]=q.x; l1[1]=q.y; l1[2]=q.z; l1[3]=q.w;
    q = fp[3]; l1[4]=q.x; l1[5]=q.y; l1[6]=q.z; l1[7]=q.w;
    q = fp[4]; l2[0]=q.x; l2[1]=q.y; l2[2]=q.z; l2[3]=q.w;
    q = fp[5]; l2[4]=q.x; l2[5]=q.y; l2[6]=q.z; l2[7]=q.w;
    q = fp[6]; l3[0]=q.x; l3[1]=q.y; l3[2]=q.z; l3[3]=q.w;
    q = fp[7]; l3[4]=q.x; l3[5]=q.y; l3[6]=q.z; l3[7]=q.w;
    merge8(l0, l1, t0); merge8(l2, l3, t1); merge8(t0, t1, m);

    float p = pos_sim[row], fs = 0.f;
    #pragma unroll
    for (int k = 0; k < 8; ++k) {
        float h = fmaxf(p - m[k] + 1.0f, 0.f);
        fs += h * h;
    }

    const float4* ap = (const float4*)(sosAP + (size_t)row * 16);
    q = ap[0]; l0[0]=q.x; l0[1]=q.y; l0[2]=q.z; l0[3]=q.w;
    q = ap[1]; l0[4]=q.x; l0[5]=q.y; l0[6]=q.z; l0[7]=q.w;
    q = ap[2]; l1[0]=q.x; l1[1]=q.y; l1[2]=q.z; l1[3]=q.w;
    q = ap[3]; l1[4]=q.x; l1[5]=q.y; l1[6]=q.z; l1[7]=q.w;
    merge8(l0, l1, t0);
    const float4* bp = (const float4*)(sosBP + (size_t)row * 16);
    q = bp[0]; l2[0]=q.x; l2[1]=q.y; l2[2]=q.z; l2[3]=q.w;
    q = bp[1]; l2[4]=q.x; l2[5]=q.y; l2[6]=q.z; l2[7]=q.w;
    q = bp[2]; l3[0]=q.x; l3[1]=q.y; l3[2]=q.z; l3[3]=q.w;
    q = bp[3]; l3[4]=q.x; l3[5]=q.y; l3[6]=q.z; l3[7]=q.w;
    merge8(l2, l3, t1);

    float acc = 0.f;
    #pragma unroll
    for (int k = 0; k < 8; ++k) {
        float d = t0[k] - t1[k];
        acc += d * d;
    }
    frow[row] = fs;
    srow[row] = sqrtf(acc);
}

__global__ __launch_bounds__(256) void freduce_kernel(
    const float* __restrict__ frow, const float* __restrict__ srow,
    float* __restrict__ outp)
{
    __shared__ float sf[256], ss[256];
    int t = threadIdx.x;
    float f = 0.f, s = 0.f;
    for (int i = t; i < NB * NN; i += 256) { f += frow[i]; s += srow[i]; }
    sf[t] = f; ss[t] = s;
    __syncthreads();
    for (int o = 128; o > 0; o >>= 1) {
        if (t < o) { sf[t] += sf[t + o]; ss[t] += ss[t + o]; }
        __syncthreads();
    }
    if (t == 0)
        outp[0] = sf[0] / (float)(NB * NN * 8) + ss[0] / (float)(NB * NN);
}

extern "C" void kernel_launch(void* const* d_in, const int* in_sizes, int n_in,
                              void* d_out, int out_size, void* d_ws, size_t ws_size,
                              hipStream_t stream) {
    const float* kp1      = (const float*)d_in[0];
    const float* w_kp1    = (const float*)d_in[1];
    const float* kp1_desc = (const float*)d_in[2];
    const float* desc2    = (const float*)d_in[3];
    const float* homo     = (const float*)d_in[4];
    float* outp = (float*)d_out;

    char* ws = (char*)d_ws;
    size_t o = 0;
    unsigned short* khi  = (unsigned short*)(ws + o); o += (size_t)NB * NN * NCCH * 2;
    unsigned short* klo  = (unsigned short*)(ws + o); o += (size_t)NB * NN * NCCH * 2;
    unsigned short* whi  = (unsigned short*)(ws + o); o += (size_t)NB * NN * NCCH * 2;
    unsigned short* wlo  = (unsigned short*)(ws + o); o += (size_t)NB * NN * NCCH * 2;
    unsigned short* d2hi = (unsigned short*)(ws + o); o += (size_t)NB * NHW * NCCH * 2;
    unsigned short* d2lo = (unsigned short*)(ws + o); o += (size_t)NB * NHW * NCCH * 2;
    float* pos_sim = (float*)(ws + o); o += (size_t)NB * NN * 4;
    float* fosP    = (float*)(ws + o); o += (size_t)NB * NN * 32 * 4;
    float* sosAP   = (float*)(ws + o); o += (size_t)NB * NN * 16 * 4;
    float* sosBP   = (float*)(ws + o); o += (size_t)NB * NN * 16 * 4;
    float* frow    = (float*)(ws + o); o += (size_t)NB * NN * 4;
    float* srow    = (float*)(ws + o); o += (size_t)NB * NN * 4;
    int*   mask_id = (int*)(ws + o);   o += (size_t)NB * NN * 16 * 4;
    float* d2T     = (float*)(ws + o);
    size_t need_t  = o + (size_t)NB * NHW * NCCH * 4;
    int use_t = (ws_size >= need_t) ? 1 : 0;   // constant across calls
    if (!use_t) d2T = (float*)ws;              // valid dummy, never read

    d2split_kernel<<<NB * 256, 256, 0, stream>>>(desc2, d2hi, d2lo, d2T, use_t);
    sample_mask_kernel<<<1040, 256, 0, stream>>>(kp1, w_kp1, kp1_desc, desc2,
                                                 d2T, use_t, homo,
                                                 khi, klo, whi, wlo,
                                                 pos_sim, mask_id);
    simtop_fused<<<1024, 256, 0, stream>>>(khi, klo, whi, wlo, d2hi, d2lo,
                                           kp1, w_kp1, mask_id,
                                           fosP, sosAP, sosBP);
    frow_kernel<<<16, 256, 0, stream>>>(fosP, sosAP, sosBP, pos_sim, frow, srow);
    freduce_kernel<<<1, 256, 0, stream>>>(frow, srow, outp);
}

// Round 6
// 177.221 us; speedup vs baseline: 3.7511x; 1.1271x over previous
//
#include <hip/hip_runtime.h>

#define NB 4
#define NN 1024
#define NCCH 128
#define NH 64
#define NW 64
#define NHW 4096
#define CHUNK 128

// (8*sqrt(2)+0.1)^2
constexpr float RADIUS2 = 130.27274173013714f;

typedef __attribute__((ext_vector_type(8))) short short8v;   // 8 bf16 = 4 VGPR
typedef __attribute__((ext_vector_type(4))) float f32x4;

__device__ __forceinline__ unsigned short f2bf(float f) {   // RNE f32->bf16
    unsigned u = __float_as_uint(f);
    unsigned r = u + 0x7FFFu + ((u >> 16) & 1u);
    return (unsigned short)(r >> 16);
}
__device__ __forceinline__ float bf2f(unsigned short h) {
    return __uint_as_float(((unsigned)h) << 16);
}

// ---------------------------------------------------------------------------
// bitonic partial merge: two ascending sorted-8 lists -> smallest 8 ascending
// ---------------------------------------------------------------------------
__device__ __forceinline__ void bsort8(float* v) {
    #pragma unroll
    for (int d = 4; d >= 1; d >>= 1) {
        #pragma unroll
        for (int i = 0; i < 8; ++i) {
            if ((i & d) == 0) {
                float x = v[i], y = v[i + d];
                v[i] = fminf(x, y);
                v[i + d] = fmaxf(x, y);
            }
        }
    }
}
__device__ __forceinline__ void merge8(const float* a, const float* b, float* o) {
    #pragma unroll
    for (int k = 0; k < 8; ++k) o[k] = fminf(a[k], b[7 - k]);
    bsort8(o);
}

// ---------------------------------------------------------------------------
// 4 nearest grid-cell centers; strict '<' + increasing linear id replicates
// jax.lax.top_k tie-breaking.
// ---------------------------------------------------------------------------
__device__ __forceinline__ void nearest4(float x, float y, int out_ids[4]) {
    float u = x * 0.125f - 0.5f;
    float v = y * 0.125f - 0.5f;
    u = fminf(fmaxf(u, -1e6f), 1e6f);
    v = fminf(fmaxf(v, -1e6f), 1e6f);
    int iu = (int)floorf(u);
    int iv = (int)floorf(v);
    int xlo = min(max(iu - 2, 0), 60);
    int xhi = max(min(iu + 3, 63), 3);
    int ylo = min(max(iv - 2, 0), 60);
    int yhi = max(min(iv + 3, 63), 3);
    float bd0 = 1e30f, bd1 = 1e30f, bd2 = 1e30f, bd3 = 1e30f;
    int bi0 = 0, bi1 = 0, bi2 = 0, bi3 = 0;
    for (int yy = ylo; yy <= yhi; ++yy) {
        float dy = y - ((float)yy + 0.5f) * 8.0f;
        float dy2 = dy * dy;
        for (int xx = xlo; xx <= xhi; ++xx) {
            float dx = x - ((float)xx + 0.5f) * 8.0f;
            float d = dx * dx + dy2;
            int id = (yy << 6) | xx;
            if (d < bd3) {
                if (d < bd2) {
                    bd3 = bd2; bi3 = bi2;
                    if (d < bd1) {
                        bd2 = bd1; bi2 = bi1;
                        if (d < bd0) { bd1 = bd0; bi1 = bi0; bd0 = d; bi0 = id; }
                        else         { bd1 = d;  bi1 = id; }
                    } else { bd2 = d; bi2 = id; }
                } else { bd3 = d; bi3 = id; }
            }
        }
    }
    out_ids[0] = bi0; out_ids[1] = bi1; out_ids[2] = bi2; out_ids[3] = bi3;
}

// ---------------------------------------------------------------------------
// d2split: desc2 [B][C][HW] -> bf16 hi/lo in [B][HW][C]; optionally also an
// exact f32 transposed copy d2T [B][HW][C] (for coalesced sampling).
// ---------------------------------------------------------------------------
__global__ __launch_bounds__(256) void d2split_kernel(
    const float* __restrict__ desc2,
    unsigned short* __restrict__ d2hi, unsigned short* __restrict__ d2lo,
    float* __restrict__ d2T, int use_t)
{
    __shared__ float sT[64][33];
    int bid = blockIdx.x;
    int b = bid >> 8;
    int rem = bid & 255;
    int hw0 = (rem >> 2) * 64;
    int c0 = (rem & 3) * 32;
    int t = threadIdx.x;

    {
        int lane = t & 63, cg = t >> 6;
        const float* src = desc2 + (size_t)b * NCCH * NHW + hw0 + lane;
        #pragma unroll
        for (int i = 0; i < 8; ++i) {
            int cl = cg * 8 + i;
            sT[lane][cl] = src[(size_t)(c0 + cl) * NHW];
        }
    }
    __syncthreads();
    {
        int hw = t >> 2, q = t & 3;
        size_t base = ((size_t)b * NHW + hw0 + hw) * NCCH + c0 + q * 8;
        unsigned short hb[8], lb[8];
        float fb[8];
        #pragma unroll
        for (int i = 0; i < 8; ++i) {
            float f = sT[hw][q * 8 + i];
            unsigned short h = f2bf(f);
            hb[i] = h;
            lb[i] = f2bf(f - bf2f(h));
            fb[i] = f;
        }
        *(short8v*)(d2hi + base) = *(short8v*)hb;
        *(short8v*)(d2lo + base) = *(short8v*)lb;
        if (use_t) {
            *(float4*)(d2T + base) = *(float4*)&fb[0];
            *(float4*)(d2T + base + 4) = *(float4*)&fb[4];
        }
    }
}

// ---------------------------------------------------------------------------
// sample+mask fused. blocks [0,1024): wave-per-keypoint bilinear sample,
// L2-normalize, positive_sim, bf16 hi/lo splits of kp1_desc and w_desc.
// blocks [1024,1040): penalty mask ids (thread-per-keypoint).
// ---------------------------------------------------------------------------
__global__ __launch_bounds__(256) void sample_mask_kernel(
    const float* __restrict__ kp1, const float* __restrict__ w_kp1,
    const float* __restrict__ kp1_desc, const float* __restrict__ desc2,
    const float* __restrict__ d2T, int use_t,
    const float* __restrict__ homo,
    unsigned short* __restrict__ khi, unsigned short* __restrict__ klo,
    unsigned short* __restrict__ whi, unsigned short* __restrict__ wlo,
    float* __restrict__ pos_sim, int* __restrict__ mask_ids)
{
    int bid = blockIdx.x;
    if (bid >= 1024) {                 // ---- mask path ----
        int g = (bid - 1024) * 256 + threadIdx.x;
        if (g >= NB * NN) return;
        int b = g >> 10;
        float x = kp1[g * 2], y = kp1[g * 2 + 1];
        const float* H = homo + b * 9;
        int c4[4];
        nearest4(x, y, c4);
        int out[16];
        #pragma unroll
        for (int k = 0; k < 4; ++k) {
            int id = c4[k];
            float cx = ((float)(id & 63) + 0.5f) * 8.0f;
            float cy = ((float)(id >> 6) + 0.5f) * 8.0f;
            float q0 = H[0] * cx + H[1] * cy + H[2];
            float q1 = H[3] * cx + H[4] * cy + H[5];
            float q2 = H[6] * cx + H[7] * cy + H[8];
            float iz = 1.0f / (q2 + 1e-8f);
            nearest4(q0 * iz, q1 * iz, out + 4 * k);
        }
        #pragma unroll
        for (int k = 0; k < 16; ++k) mask_ids[(size_t)g * 16 + k] = out[k];
        return;
    }

    // ---- sample path: one wave per keypoint ----
    int lane = threadIdx.x & 63;
    int wid = bid * 4 + (threadIdx.x >> 6);
    int b = wid >> 10;

    float px = w_kp1[wid * 2 + 0], py = w_kp1[wid * 2 + 1];
    float fx = px * 0.125f - 0.5f, fy = py * 0.125f - 0.5f;
    float fx0 = floorf(fx), fy0 = floorf(fy);
    float wx = fx - fx0, wy = fy - fy0;
    int x0 = min(max((int)fx0, 0), NW - 1);
    int x1 = min(x0 + 1, NW - 1);
    int y0 = min(max((int)fy0, 0), NH - 1);
    int y1 = min(y0 + 1, NH - 1);
    float w00 = (1.f - wx) * (1.f - wy), w01 = wx * (1.f - wy);
    float w10 = (1.f - wx) * wy,         w11 = wx * wy;
    int i00 = y0 * NW + x0, i01 = y0 * NW + x1;
    int i10 = y1 * NW + x0, i11 = y1 * NW + x1;

    float o0, o1;
    if (use_t) {                       // coalesced: [HW][C] rows
        const float* base = d2T + (size_t)b * NHW * NCCH;
        const float* r00 = base + (size_t)i00 * NCCH;
        const float* r01 = base + (size_t)i01 * NCCH;
        const float* r10 = base + (size_t)i10 * NCCH;
        const float* r11 = base + (size_t)i11 * NCCH;
        o0 = w00 * r00[lane] + w01 * r01[lane] + w10 * r10[lane] + w11 * r11[lane];
        o1 = w00 * r00[lane + 64] + w01 * r01[lane + 64]
           + w10 * r10[lane + 64] + w11 * r11[lane + 64];
    } else {                           // fallback: original [C][HW] gather
        const float* d2 = desc2 + (size_t)b * NCCH * NHW;
        const float* p0 = d2 + (size_t)lane * NHW;
        const float* p1 = d2 + (size_t)(lane + 64) * NHW;
        o0 = w00 * p0[i00] + w01 * p0[i01] + w10 * p0[i10] + w11 * p0[i11];
        o1 = w00 * p1[i00] + w01 * p1[i01] + w10 * p1[i10] + w11 * p1[i11];
    }
    float nrm = o0 * o0 + o1 * o1;
    #pragma unroll
    for (int off = 32; off > 0; off >>= 1) nrm += __shfl_xor(nrm, off, 64);
    float inv = 1.0f / (sqrtf(nrm) + 1e-8f);
    o0 *= inv; o1 *= inv;

    float a0 = kp1_desc[(size_t)wid * NCCH + lane];
    float a1 = kp1_desc[(size_t)wid * NCCH + lane + 64];
    float dot = a0 * o0 + a1 * o1;
    #pragma unroll
    for (int off = 32; off > 0; off >>= 1) dot += __shfl_xor(dot, off, 64);

    size_t base = (size_t)wid * NCCH;
    unsigned short h;
    h = f2bf(a0); khi[base + lane] = h;      klo[base + lane] = f2bf(a0 - bf2f(h));
    h = f2bf(a1); khi[base + lane + 64] = h; klo[base + lane + 64] = f2bf(a1 - bf2f(h));
    h = f2bf(o0); whi[base + lane] = h;      wlo[base + lane] = f2bf(o0 - bf2f(h));
    h = f2bf(o1); whi[base + lane + 64] = h; wlo[base + lane + 64] = f2bf(o1 - bf2f(h));
    if (lane == 0) pos_sim[wid] = 2.0f - 2.0f * dot;
}

// ---------------------------------------------------------------------------
// Fused sim+top8, MFMA, 32 rows/block, XCD-localized work placement.
// 32 work groups (16 FOS (b,cs) + 8 SOS-A (b,cs) + 8 SOS-B) x 32 rowgroups.
// bid = xcd + 8*slot; slot = gl*32 + rg, gl in [0,4):
//   gl 0,1 -> FOS group g = xcd + 8*gl: b=g>>2, cs=g&3 (col-slice of 1024)
//   gl 2   -> SOS-A group xcd: b=xcd>>1, cs=xcd&1 (col-slice of 512)
//   gl 3   -> SOS-B group xcd: likewise
// All 32 rowgroups of a group share one B panel -> panel stays in that XCD's
// L2 (~3 MB/XCD resident). Chunked by 128 cols; per-wave 32 cols; 2 register-
// resident A row-tiles; 3-term bf16 split (hh,hl,lh per accumulator).
// ---------------------------------------------------------------------------
__global__ __launch_bounds__(256, 4) void simtop_fused(
    const unsigned short* __restrict__ khi, const unsigned short* __restrict__ klo,
    const unsigned short* __restrict__ whi, const unsigned short* __restrict__ wlo,
    const unsigned short* __restrict__ d2hi, const unsigned short* __restrict__ d2lo,
    const float* __restrict__ kp1, const float* __restrict__ w_kp1,
    const int* __restrict__ mask_ids,
    float* __restrict__ fosP, float* __restrict__ sosAP, float* __restrict__ sosBP)
{
    __shared__ float sChunk[32][CHUNK + 1];   // 16.5 KB; aliased as merge buffer
    __shared__ int   sMask[32][16];
    __shared__ float sCx[CHUNK], sCy[CHUNK];
    __shared__ float sRx[32], sRy[32];

    int tid = threadIdx.x;
    int bid = blockIdx.x;
    int xcd = bid & 7, slot = bid >> 3;
    int gl = slot >> 5, rg = slot & 31;

    int mode, cs, b, nchunk, colbase, outStride;
    const unsigned short *AH, *AL, *BH, *BL;
    const float* coords = nullptr;
    float* outP;
    if (gl < 2) {
        int g = xcd + 8 * gl;
        mode = 0; b = g >> 2; cs = g & 3;
        nchunk = 8; colbase = cs * 1024;
        AH = khi + (size_t)b * NN * NCCH;  AL = klo + (size_t)b * NN * NCCH;
        BH = d2hi + (size_t)b * NHW * NCCH; BL = d2lo + (size_t)b * NHW * NCCH;
        outP = fosP; outStride = 32;
    } else if (gl == 2) {
        mode = 1; b = xcd >> 1; cs = xcd & 1;
        nchunk = 4; colbase = cs * 512;
        AH = khi + (size_t)b * NN * NCCH;  AL = klo + (size_t)b * NN * NCCH;
        BH = AH; BL = AL;
        coords = kp1; outP = sosAP; outStride = 16;
    } else {
        mode = 2; b = xcd >> 1; cs = xcd & 1;
        nchunk = 4; colbase = cs * 512;
        AH = whi + (size_t)b * NN * NCCH;  AL = wlo + (size_t)b * NN * NCCH;
        BH = AH; BL = AL;
        coords = w_kp1; outP = sosBP; outStride = 16;
    }
    int row0 = rg * 32;

    int lane = tid & 63, wg = tid >> 6;
    int lrow = lane & 15, lgrp = lane >> 4;
    int srow = tid & 31, sgrp = tid >> 5;     // selection: 8 threads/row, 16 cols each

    // A fragments: 2 row-tiles x 4 k-steps, hi+lo
    short8v ahi[2][4], alo[2][4];
    #pragma unroll
    for (int rt = 0; rt < 2; ++rt) {
        const unsigned short* aH = AH + (size_t)(row0 + rt * 16 + lrow) * NCCH + lgrp * 8;
        const unsigned short* aL = AL + (size_t)(row0 + rt * 16 + lrow) * NCCH + lgrp * 8;
        #pragma unroll
        for (int s = 0; s < 4; ++s) {
            ahi[rt][s] = *(const short8v*)(aH + s * 32);
            alo[rt][s] = *(const short8v*)(aL + s * 32);
        }
    }

    if (mode == 0) {
        for (int e = tid; e < 512; e += 256)
            sMask[e >> 4][e & 15] =
                mask_ids[((size_t)b * NN + row0 + (e >> 4)) * 16 + (e & 15)];
    } else if (tid < 32) {
        sRx[tid] = coords[((size_t)b * NN + row0 + tid) * 2];
        sRy[tid] = coords[((size_t)b * NN + row0 + tid) * 2 + 1];
    }

    float loc[8];
    #pragma unroll
    for (int k = 0; k < 8; ++k) loc[k] = 1e30f;

    for (int ch = 0; ch < nchunk; ++ch) {
        int cglob = colbase + ch * CHUNK;
        __syncthreads();                 // sChunk free from previous selection

        int colq = cglob + wg * 32;      // this wave's 32-col slice (2 nt tiles)
        {
            const unsigned short* b0H = BH + (size_t)(colq + lrow) * NCCH + lgrp * 8;
            const unsigned short* b0L = BL + (size_t)(colq + lrow) * NCCH + lgrp * 8;
            const unsigned short* b1H = BH + (size_t)(colq + 16 + lrow) * NCCH + lgrp * 8;
            const unsigned short* b1L = BL + (size_t)(colq + 16 + lrow) * NCCH + lgrp * 8;
            f32x4 a00 = {0.f, 0.f, 0.f, 0.f}, a01 = {0.f, 0.f, 0.f, 0.f};
            f32x4 a10 = {0.f, 0.f, 0.f, 0.f}, a11 = {0.f, 0.f, 0.f, 0.f};
            #pragma unroll
            for (int s = 0; s < 4; ++s) {
                short8v bh0 = *(const short8v*)(b0H + s * 32);
                short8v bl0 = *(const short8v*)(b0L + s * 32);
                short8v bh1 = *(const short8v*)(b1H + s * 32);
                short8v bl1 = *(const short8v*)(b1L + s * 32);
                // 4 independent chains; per-acc order (hh,hl,lh) == prior numerics
                a00 = __builtin_amdgcn_mfma_f32_16x16x32_bf16(ahi[0][s], bh0, a00, 0, 0, 0);
                a10 = __builtin_amdgcn_mfma_f32_16x16x32_bf16(ahi[1][s], bh0, a10, 0, 0, 0);
                a01 = __builtin_amdgcn_mfma_f32_16x16x32_bf16(ahi[0][s], bh1, a01, 0, 0, 0);
                a11 = __builtin_amdgcn_mfma_f32_16x16x32_bf16(ahi[1][s], bh1, a11, 0, 0, 0);
                a00 = __builtin_amdgcn_mfma_f32_16x16x32_bf16(ahi[0][s], bl0, a00, 0, 0, 0);
                a10 = __builtin_amdgcn_mfma_f32_16x16x32_bf16(ahi[1][s], bl0, a10, 0, 0, 0);
                a01 = __builtin_amdgcn_mfma_f32_16x16x32_bf16(ahi[0][s], bl1, a01, 0, 0, 0);
                a11 = __builtin_amdgcn_mfma_f32_16x16x32_bf16(ahi[1][s], bl1, a11, 0, 0, 0);
                a00 = __builtin_amdgcn_mfma_f32_16x16x32_bf16(alo[0][s], bh0, a00, 0, 0, 0);
                a10 = __builtin_amdgcn_mfma_f32_16x16x32_bf16(alo[1][s], bh0, a10, 0, 0, 0);
                a01 = __builtin_amdgcn_mfma_f32_16x16x32_bf16(alo[0][s], bh1, a01, 0, 0, 0);
                a11 = __builtin_amdgcn_mfma_f32_16x16x32_bf16(alo[1][s], bh1, a11, 0, 0, 0);
            }
            #pragma unroll
            for (int r = 0; r < 4; ++r) {
                sChunk[lgrp * 4 + r][wg * 32 + lrow]           = 2.0f - 2.0f * a00[r];
                sChunk[16 + lgrp * 4 + r][wg * 32 + lrow]      = 2.0f - 2.0f * a10[r];
                sChunk[lgrp * 4 + r][wg * 32 + 16 + lrow]      = 2.0f - 2.0f * a01[r];
                sChunk[16 + lgrp * 4 + r][wg * 32 + 16 + lrow] = 2.0f - 2.0f * a11[r];
            }
        }
        __syncthreads();

        if (mode == 0) {
            for (int e = tid; e < 512; e += 256) {
                int r = e >> 4;
                int id = sMask[r][e & 15] - cglob;
                if (id >= 0 && id < CHUNK) atomicAdd(&sChunk[r][id], 5.0f);
            }
        } else {
            if (tid < CHUNK)
                sCx[tid] = coords[((size_t)b * NN + cglob + tid) * 2];
            else
                sCy[tid - CHUNK] = coords[((size_t)b * NN + cglob + (tid - CHUNK)) * 2 + 1];
        }
        __syncthreads();

        float rx = 0.f, ry = 0.f;
        if (mode != 0) { rx = sRx[srow]; ry = sRy[srow]; }
        #pragma unroll
        for (int j = 0; j < 16; ++j) {
            int cl = sgrp * 16 + j;
            float v = sChunk[srow][cl];
            if (mode != 0) {
                float dx = rx - sCx[cl], dy = ry - sCy[cl];
                if (dx * dx + dy * dy <= RADIUS2) v += 5.0f;
            }
            if (v < loc[7]) {
                loc[7] = v;
                #pragma unroll
                for (int p = 7; p > 0; --p) {
                    if (loc[p - 1] > loc[p]) {
                        float t = loc[p - 1]; loc[p - 1] = loc[p]; loc[p] = t;
                    }
                }
            }
        }
    }

    // parallel tree merge of the 8 per-thread sorted lists per row
    __syncthreads();
    float* mg = &sChunk[0][0];           // [32][67] alias (2144 < 4128 floats)
    #pragma unroll
    for (int k = 0; k < 8; ++k) mg[srow * 67 + sgrp * 8 + k] = loc[k];
    __syncthreads();
    #pragma unroll
    for (int step = 1; step < 8; step <<= 1) {
        if ((sgrp & (2 * step - 1)) == 0) {
            float a[8], bb[8], o[8];
            #pragma unroll
            for (int k = 0; k < 8; ++k) {
                a[k]  = mg[srow * 67 + sgrp * 8 + k];
                bb[k] = mg[srow * 67 + (sgrp + step) * 8 + k];
            }
            merge8(a, bb, o);
            #pragma unroll
            for (int k = 0; k < 8; ++k) mg[srow * 67 + sgrp * 8 + k] = o[k];
        }
        __syncthreads();
    }
    if (tid < 32) {
        size_t row = (size_t)b * NN + row0 + tid;
        #pragma unroll
        for (int k = 0; k < 8; ++k)
            outP[row * outStride + cs * 8 + k] = mg[tid * 67 + k];
    }
}

// ---------------------------------------------------------------------------
// Per-row finalize: merge partial top-8 lists, hinge (FOS) and sqrt-diff (SOS)
// ---------------------------------------------------------------------------
__global__ __launch_bounds__(256) void frow_kernel(
    const float* __restrict__ fosP, const float* __restrict__ sosAP,
    const float* __restrict__ sosBP, const float* __restrict__ pos_sim,
    float* __restrict__ frow, float* __restrict__ srow)
{
    int row = blockIdx.x * 256 + threadIdx.x;
    if (row >= NB * NN) return;

    float l0[8], l1[8], l2[8], l3[8], t0[8], t1[8], m[8];
    const float4* fp = (const float4*)(fosP + (size_t)row * 32);
    float4 q;
    q = fp[0]; l0[0]=q.x; l0[1]=q.y; l0[2]=q.z; l0[3]=q.w;
    q = fp[1]; l0[4]=q.x; l0[5]=q.y; l0[6]=q.z; l0[7]=q.w;
    q = fp[2]; l1[0]=q.x; l1[1]=q.y; l1[2]=q.z; l1[3]=q.w;
    q = fp[3]; l1[4]=q.x; l1[5]=q.y; l1[6]=q.z; l1[7]=q.w;
    q = fp[4]; l2[0]=q.x; l2[1]=q.y; l2[2]=q.z; l2[3]=q.w;
    q = fp[5]; l2[4]=q.x; l2[5]=q.y; l2[6]=q.z; l2[7]=q.w;
    q = fp[6]; l3[0]=q.x; l3[1]=q.y; l3[2]=q.z; l3[3]=q.w;
    q = fp[7]; l3[4]=q.x; l3[5]=q.y; l3[6]=q.z; l3[7]=q.w;
    merge8(l0, l1, t0); merge8(l2, l3, t1); merge8(t0, t1, m);

    float p = pos_sim[row], fs = 0.f;
    #pragma unroll
    for (int k = 0; k < 8; ++k) {
        float h = fmaxf(p - m[k] + 1.0f, 0.f);
        fs += h * h;
    }

    const float4* ap = (const float4*)(sosAP + (size_t)row * 16);
    q = ap[0]; l0[0]=q.x; l0[1]=q.y; l0[2]=q.z; l0[3]=q.w;
    q = ap[1]; l0[4]=q.x; l0[5]=q.y; l0[6]=q.z; l0[7]=q.w;
    q = ap[2]; l1[0]=q.x; l1[1]=q.y; l1[2]=q.z; l1[3]=q.w;
    q = ap[3]; l1[4]=q.x; l1[5]=q.y; l1[6]=q.z; l1[7]=q.w;
    merge8(l0, l1, t0);
    const float4* bp = (const float4*)(sosBP + (size_t)row * 16);
    q = bp[0]; l2[0]=q.x; l2[1]=q.y; l2[2]=q.z; l2[3]=q.w;
    q = bp[1]; l2[4]=q.x; l2[5]=q.y; l2[6]=q.z; l2[7]=q.w;
    q = bp[2]; l3[0]=q.x; l3[1]=q.y; l3[2]=q.z; l3[3]=q.w;
    q = bp[3]; l3[4]=q.x; l3[5]=q.y; l3[6]=q.z; l3[7]=q.w;
    merge8(l2, l3, t1);

    float acc = 0.f;
    #pragma unroll
    for (int k = 0; k < 8; ++k) {
        float d = t0[k] - t1[k];
        acc += d * d;
    }
    frow[row] = fs;
    srow[row] = sqrtf(acc);
}

__global__ __launch_bounds__(256) void freduce_kernel(
    const float* __restrict__ frow, const float* __restrict__ srow,
    float* __restrict__ outp)
{
    __shared__ float sf[256], ss[256];
    int t = threadIdx.x;
    float f = 0.f, s = 0.f;
    for (int i = t; i < NB * NN; i += 256) { f += frow[i]; s += srow[i]; }
    sf[t] = f; ss[t] = s;
    __syncthreads();
    for (int o = 128; o > 0; o >>= 1) {
        if (t < o) { sf[t] += sf[t + o]; ss[t] += ss[t + o]; }
        __syncthreads();
    }
    if (t == 0)
        outp[0] = sf[0] / (float)(NB * NN * 8) + ss[0] / (float)(NB * NN);
}

extern "C" void kernel_launch(void* const* d_in, const int* in_sizes, int n_in,
                              void* d_out, int out_size, void* d_ws, size_t ws_size,
                              hipStream_t stream) {
    const float* kp1      = (const float*)d_in[0];
    const float* w_kp1    = (const float*)d_in[1];
    const float* kp1_desc = (const float*)d_in[2];
    const float* desc2    = (const float*)d_in[3];
    const float* homo     = (const float*)d_in[4];
    float* outp = (float*)d_out;

    char* ws = (char*)d_ws;
    size_t o = 0;
    unsigned short* khi  = (unsigned short*)(ws + o); o += (size_t)NB * NN * NCCH * 2;
    unsigned short* klo  = (unsigned short*)(ws + o); o += (size_t)NB * NN * NCCH * 2;
    unsigned short* whi  = (unsigned short*)(ws + o); o += (size_t)NB * NN * NCCH * 2;
    unsigned short* wlo  = (unsigned short*)(ws + o); o += (size_t)NB * NN * NCCH * 2;
    unsigned short* d2hi = (unsigned short*)(ws + o); o += (size_t)NB * NHW * NCCH * 2;
    unsigned short* d2lo = (unsigned short*)(ws + o); o += (size_t)NB * NHW * NCCH * 2;
    float* pos_sim = (float*)(ws + o); o += (size_t)NB * NN * 4;
    float* fosP    = (float*)(ws + o); o += (size_t)NB * NN * 32 * 4;
    float* sosAP   = (float*)(ws + o); o += (size_t)NB * NN * 16 * 4;
    float* sosBP   = (float*)(ws + o); o += (size_t)NB * NN * 16 * 4;
    float* frow    = (float*)(ws + o); o += (size_t)NB * NN * 4;
    float* srow    = (float*)(ws + o); o += (size_t)NB * NN * 4;
    int*   mask_id = (int*)(ws + o);   o += (size_t)NB * NN * 16 * 4;
    float* d2T     = (float*)(ws + o);
    size_t need_t  = o + (size_t)NB * NHW * NCCH * 4;
    int use_t = (ws_size >= need_t) ? 1 : 0;   // constant across calls
    if (!use_t) d2T = (float*)ws;              // valid dummy, never read

    d2split_kernel<<<NB * 256, 256, 0, stream>>>(desc2, d2hi, d2lo, d2T, use_t);
    sample_mask_kernel<<<1040, 256, 0, stream>>>(kp1, w_kp1, kp1_desc, desc2,
                                                 d2T, use_t, homo,
                                                 khi, klo, whi, wlo,
                                                 pos_sim, mask_id);
    simtop_fused<<<1024, 256, 0, stream>>>(khi, klo, whi, wlo, d2hi, d2lo,
                                           kp1, w_kp1, mask_id,
                                           fosP, sosAP, sosBP);
    frow_kernel<<<16, 256, 0, stream>>>(fosP, sosAP, sosBP, pos_sim, frow, srow);
    freduce_kernel<<<1, 256, 0, stream>>>(frow, srow, outp);
}

// Round 10
// 174.666 us; speedup vs baseline: 3.8059x; 1.0146x over previous
//
#include <hip/hip_runtime.h>

#define NB 4
#define NN 1024
#define NCCH 128
#define NH 64
#define NW 64
#define NHW 4096
#define CHUNK 128

// (8*sqrt(2)+0.1)^2
constexpr float RADIUS2 = 130.27274173013714f;

typedef __attribute__((ext_vector_type(8))) short short8v;   // 8 bf16 = 4 VGPR
typedef __attribute__((ext_vector_type(4))) float f32x4;

__device__ __forceinline__ unsigned short f2bf(float f) {   // RNE f32->bf16
    unsigned u = __float_as_uint(f);
    unsigned r = u + 0x7FFFu + ((u >> 16) & 1u);
    return (unsigned short)(r >> 16);
}
__device__ __forceinline__ float bf2f(unsigned short h) {
    return __uint_as_float(((unsigned)h) << 16);
}

// ---------------------------------------------------------------------------
// bitonic partial merge: two ascending sorted-8 lists -> smallest 8 ascending
// ---------------------------------------------------------------------------
__device__ __forceinline__ void bsort8(float* v) {
    #pragma unroll
    for (int d = 4; d >= 1; d >>= 1) {
        #pragma unroll
        for (int i = 0; i < 8; ++i) {
            if ((i & d) == 0) {
                float x = v[i], y = v[i + d];
                v[i] = fminf(x, y);
                v[i + d] = fmaxf(x, y);
            }
        }
    }
}
__device__ __forceinline__ void merge8(const float* a, const float* b, float* o) {
    #pragma unroll
    for (int k = 0; k < 8; ++k) o[k] = fminf(a[k], b[7 - k]);
    bsort8(o);
}

// ---------------------------------------------------------------------------
// 4 nearest grid-cell centers; strict '<' + increasing linear id replicates
// jax.lax.top_k tie-breaking.
// ---------------------------------------------------------------------------
__device__ __forceinline__ void nearest4(float x, float y, int out_ids[4]) {
    float u = x * 0.125f - 0.5f;
    float v = y * 0.125f - 0.5f;
    u = fminf(fmaxf(u, -1e6f), 1e6f);
    v = fminf(fmaxf(v, -1e6f), 1e6f);
    int iu = (int)floorf(u);
    int iv = (int)floorf(v);
    int xlo = min(max(iu - 2, 0), 60);
    int xhi = max(min(iu + 3, 63), 3);
    int ylo = min(max(iv - 2, 0), 60);
    int yhi = max(min(iv + 3, 63), 3);
    float bd0 = 1e30f, bd1 = 1e30f, bd2 = 1e30f, bd3 = 1e30f;
    int bi0 = 0, bi1 = 0, bi2 = 0, bi3 = 0;
    for (int yy = ylo; yy <= yhi; ++yy) {
        float dy = y - ((float)yy + 0.5f) * 8.0f;
        float dy2 = dy * dy;
        for (int xx = xlo; xx <= xhi; ++xx) {
            float dx = x - ((float)xx + 0.5f) * 8.0f;
            float d = dx * dx + dy2;
            int id = (yy << 6) | xx;
            if (d < bd3) {
                if (d < bd2) {
                    bd3 = bd2; bi3 = bi2;
                    if (d < bd1) {
                        bd2 = bd1; bi2 = bi1;
                        if (d < bd0) { bd1 = bd0; bi1 = bi0; bd0 = d; bi0 = id; }
                        else         { bd1 = d;  bi1 = id; }
                    } else { bd2 = d; bi2 = id; }
                } else { bd3 = d; bi3 = id; }
            }
        }
    }
    out_ids[0] = bi0; out_ids[1] = bi1; out_ids[2] = bi2; out_ids[3] = bi3;
}

// ---------------------------------------------------------------------------
// prep kernel: three independent phases in one dispatch (run concurrently):
//   blocks [0,1024):    d2split — desc2 [B][C][HW] -> bf16 hi/lo [B][HW][C]
//   blocks [1024,2048): sample  — bilinear sample (exact gather from desc2),
//                       L2-normalize, positive_sim, bf16 hi/lo of kp1_desc
//                       and w_desc (wave per keypoint)
//   blocks [2048,2064): mask    — 16 penalty cell ids per keypoint
// ---------------------------------------------------------------------------
__global__ __launch_bounds__(256) void prep_kernel(
    const float* __restrict__ kp1, const float* __restrict__ w_kp1,
    const float* __restrict__ kp1_desc, const float* __restrict__ desc2,
    const float* __restrict__ homo,
    unsigned short* __restrict__ khi, unsigned short* __restrict__ klo,
    unsigned short* __restrict__ whi, unsigned short* __restrict__ wlo,
    unsigned short* __restrict__ d2hi, unsigned short* __restrict__ d2lo,
    float* __restrict__ pos_sim, int* __restrict__ mask_ids)
{
    __shared__ float sT[64][33];
    int bid = blockIdx.x;
    int t = threadIdx.x;

    if (bid < 1024) {                  // ---- d2split ----
        int b = bid >> 8;
        int rem = bid & 255;
        int hw0 = (rem >> 2) * 64;
        int c0 = (rem & 3) * 32;
        {
            int lane = t & 63, cg = t >> 6;
            const float* src = desc2 + (size_t)b * NCCH * NHW + hw0 + lane;
            #pragma unroll
            for (int i = 0; i < 8; ++i) {
                int cl = cg * 8 + i;
                sT[lane][cl] = src[(size_t)(c0 + cl) * NHW];
            }
        }
        __syncthreads();
        {
            int hw = t >> 2, q = t & 3;
            size_t base = ((size_t)b * NHW + hw0 + hw) * NCCH + c0 + q * 8;
            unsigned short hb[8], lb[8];
            #pragma unroll
            for (int i = 0; i < 8; ++i) {
                float f = sT[hw][q * 8 + i];
                unsigned short h = f2bf(f);
                hb[i] = h;
                lb[i] = f2bf(f - bf2f(h));
            }
            *(short8v*)(d2hi + base) = *(short8v*)hb;
            *(short8v*)(d2lo + base) = *(short8v*)lb;
        }
        return;
    }

    if (bid >= 2048) {                 // ---- mask ----
        int g = (bid - 2048) * 256 + t;
        if (g >= NB * NN) return;
        int b = g >> 10;
        float x = kp1[g * 2], y = kp1[g * 2 + 1];
        const float* H = homo + b * 9;
        int c4[4];
        nearest4(x, y, c4);
        int out[16];
        #pragma unroll
        for (int k = 0; k < 4; ++k) {
            int id = c4[k];
            float cx = ((float)(id & 63) + 0.5f) * 8.0f;
            float cy = ((float)(id >> 6) + 0.5f) * 8.0f;
            float q0 = H[0] * cx + H[1] * cy + H[2];
            float q1 = H[3] * cx + H[4] * cy + H[5];
            float q2 = H[6] * cx + H[7] * cy + H[8];
            float iz = 1.0f / (q2 + 1e-8f);
            nearest4(q0 * iz, q1 * iz, out + 4 * k);
        }
        #pragma unroll
        for (int k = 0; k < 16; ++k) mask_ids[(size_t)g * 16 + k] = out[k];
        return;
    }

    // ---- sample: one wave per keypoint (exact gather, round-4 numerics) ----
    int lane = t & 63;
    int wid = (bid - 1024) * 4 + (t >> 6);
    int b = wid >> 10;

    float px = w_kp1[wid * 2 + 0], py = w_kp1[wid * 2 + 1];
    float fx = px * 0.125f - 0.5f, fy = py * 0.125f - 0.5f;
    float fx0 = floorf(fx), fy0 = floorf(fy);
    float wx = fx - fx0, wy = fy - fy0;
    int x0 = min(max((int)fx0, 0), NW - 1);
    int x1 = min(x0 + 1, NW - 1);
    int y0 = min(max((int)fy0, 0), NH - 1);
    int y1 = min(y0 + 1, NH - 1);
    float w00 = (1.f - wx) * (1.f - wy), w01 = wx * (1.f - wy);
    float w10 = (1.f - wx) * wy,         w11 = wx * wy;
    int i00 = y0 * NW + x0, i01 = y0 * NW + x1;
    int i10 = y1 * NW + x0, i11 = y1 * NW + x1;

    const float* d2 = desc2 + (size_t)b * NCCH * NHW;
    const float* p0 = d2 + (size_t)lane * NHW;
    const float* p1 = d2 + (size_t)(lane + 64) * NHW;
    float o0 = w00 * p0[i00] + w01 * p0[i01] + w10 * p0[i10] + w11 * p0[i11];
    float o1 = w00 * p1[i00] + w01 * p1[i01] + w10 * p1[i10] + w11 * p1[i11];
    float nrm = o0 * o0 + o1 * o1;
    #pragma unroll
    for (int off = 32; off > 0; off >>= 1) nrm += __shfl_xor(nrm, off, 64);
    float inv = 1.0f / (sqrtf(nrm) + 1e-8f);
    o0 *= inv; o1 *= inv;

    float a0 = kp1_desc[(size_t)wid * NCCH + lane];
    float a1 = kp1_desc[(size_t)wid * NCCH + lane + 64];
    float dot = a0 * o0 + a1 * o1;
    #pragma unroll
    for (int off = 32; off > 0; off >>= 1) dot += __shfl_xor(dot, off, 64);

    size_t base = (size_t)wid * NCCH;
    unsigned short h;
    h = f2bf(a0); khi[base + lane] = h;      klo[base + lane] = f2bf(a0 - bf2f(h));
    h = f2bf(a1); khi[base + lane + 64] = h; klo[base + lane + 64] = f2bf(a1 - bf2f(h));
    h = f2bf(o0); whi[base + lane] = h;      wlo[base + lane] = f2bf(o0 - bf2f(h));
    h = f2bf(o1); whi[base + lane + 64] = h; wlo[base + lane + 64] = f2bf(o1 - bf2f(h));
    if (lane == 0) pos_sim[wid] = 2.0f - 2.0f * dot;
}

// ---------------------------------------------------------------------------
// Fused sim+top8, MFMA, 32 rows/block, XCD-localized, UNIFORM block work.
// 48 groups (32 FOS (b,cs8) + 8 SOS-A + 8 SOS-B) x 32 rowgroups = 1536 blocks.
// Every block: 4 chunks of 128 cols (512-col slice) -> zero tail imbalance,
// 6 blocks/CU. bid = xcd + 8*slot; slot = gl*32 + rg, gl in [0,6):
//   gl 0..3 -> FOS group g = xcd + 8*gl: b=g>>3, cs=g&7 (slice of 512)
//   gl 4    -> SOS-A group xcd: b=xcd>>1, cs=xcd&1 (slice of 512)
//   gl 5    -> SOS-B group xcd: likewise
// sim = 2 - 2*(A.Bt), 3-term bf16 split (hh,hl,lh per accumulator).
// 16x16x32 layouts: A[l&15][8*(l>>4)+e], B[8*(l>>4)+e][l&15],
// D: col=lane&15, row=(lane>>4)*4+reg (m89-verified).
// ---------------------------------------------------------------------------
__global__ __launch_bounds__(256, 4) void simtop_fused(
    const unsigned short* __restrict__ khi, const unsigned short* __restrict__ klo,
    const unsigned short* __restrict__ whi, const unsigned short* __restrict__ wlo,
    const unsigned short* __restrict__ d2hi, const unsigned short* __restrict__ d2lo,
    const float* __restrict__ kp1, const float* __restrict__ w_kp1,
    const int* __restrict__ mask_ids,
    float* __restrict__ fosP, float* __restrict__ sosAP, float* __restrict__ sosBP)
{
    __shared__ float sChunk[32][CHUNK + 1];   // 16.5 KB; aliased as merge buffer
    __shared__ int   sMask[32][16];
    __shared__ float sCx[CHUNK], sCy[CHUNK];
    __shared__ float sRx[32], sRy[32];

    int tid = threadIdx.x;
    int bid = blockIdx.x;
    int xcd = bid & 7, slot = bid >> 3;
    int gl = slot >> 5, rg = slot & 31;

    int mode, cs, b, colbase, outStride;
    const unsigned short *AH, *AL, *BH, *BL;
    const float* coords = nullptr;
    float* outP;
    if (gl < 4) {
        int g = xcd + 8 * gl;
        mode = 0; b = g >> 3; cs = g & 7;
        colbase = cs * 512;
        AH = khi + (size_t)b * NN * NCCH;  AL = klo + (size_t)b * NN * NCCH;
        BH = d2hi + (size_t)b * NHW * NCCH; BL = d2lo + (size_t)b * NHW * NCCH;
        outP = fosP; outStride = 64;
    } else if (gl == 4) {
        mode = 1; b = xcd >> 1; cs = xcd & 1;
        colbase = cs * 512;
        AH = khi + (size_t)b * NN * NCCH;  AL = klo + (size_t)b * NN * NCCH;
        BH = AH; BL = AL;
        coords = kp1; outP = sosAP; outStride = 16;
    } else {
        mode = 2; b = xcd >> 1; cs = xcd & 1;
        colbase = cs * 512;
        AH = whi + (size_t)b * NN * NCCH;  AL = wlo + (size_t)b * NN * NCCH;
        BH = AH; BL = AL;
        coords = w_kp1; outP = sosBP; outStride = 16;
    }
    int row0 = rg * 32;

    int lane = tid & 63, wg = tid >> 6;
    int lrow = lane & 15, lgrp = lane >> 4;
    int srow = tid & 31, sgrp = tid >> 5;     // selection: 8 threads/row, 16 cols each

    // A fragments: 2 row-tiles x 4 k-steps, hi+lo
    short8v ahi[2][4], alo[2][4];
    #pragma unroll
    for (int rt = 0; rt < 2; ++rt) {
        const unsigned short* aH = AH + (size_t)(row0 + rt * 16 + lrow) * NCCH + lgrp * 8;
        const unsigned short* aL = AL + (size_t)(row0 + rt * 16 + lrow) * NCCH + lgrp * 8;
        #pragma unroll
        for (int s = 0; s < 4; ++s) {
            ahi[rt][s] = *(const short8v*)(aH + s * 32);
            alo[rt][s] = *(const short8v*)(aL + s * 32);
        }
    }

    if (mode == 0) {
        for (int e = tid; e < 512; e += 256)
            sMask[e >> 4][e & 15] =
                mask_ids[((size_t)b * NN + row0 + (e >> 4)) * 16 + (e & 15)];
    } else if (tid < 32) {
        sRx[tid] = coords[((size_t)b * NN + row0 + tid) * 2];
        sRy[tid] = coords[((size_t)b * NN + row0 + tid) * 2 + 1];
    }

    float loc[8];
    #pragma unroll
    for (int k = 0; k < 8; ++k) loc[k] = 1e30f;

    for (int ch = 0; ch < 4; ++ch) {
        int cglob = colbase + ch * CHUNK;
        __syncthreads();                 // sChunk free from previous selection

        int colq = cglob + wg * 32;      // this wave's 32-col slice (2 nt tiles)
        {
            const unsigned short* b0H = BH + (size_t)(colq + lrow) * NCCH + lgrp * 8;
            const unsigned short* b0L = BL + (size_t)(colq + lrow) * NCCH + lgrp * 8;
            const unsigned short* b1H = BH + (size_t)(colq + 16 + lrow) * NCCH + lgrp * 8;
            const unsigned short* b1L = BL + (size_t)(colq + 16 + lrow) * NCCH + lgrp * 8;
            f32x4 a00 = {0.f, 0.f, 0.f, 0.f}, a01 = {0.f, 0.f, 0.f, 0.f};
            f32x4 a10 = {0.f, 0.f, 0.f, 0.f}, a11 = {0.f, 0.f, 0.f, 0.f};
            #pragma unroll
            for (int s = 0; s < 4; ++s) {
                short8v bh0 = *(const short8v*)(b0H + s * 32);
                short8v bl0 = *(const short8v*)(b0L + s * 32);
                short8v bh1 = *(const short8v*)(b1H + s * 32);
                short8v bl1 = *(const short8v*)(b1L + s * 32);
                // 4 independent chains; per-acc order (hh,hl,lh) == prior numerics
                a00 = __builtin_amdgcn_mfma_f32_16x16x32_bf16(ahi[0][s], bh0, a00, 0, 0, 0);
                a10 = __builtin_amdgcn_mfma_f32_16x16x32_bf16(ahi[1][s], bh0, a10, 0, 0, 0);
                a01 = __builtin_amdgcn_mfma_f32_16x16x32_bf16(ahi[0][s], bh1, a01, 0, 0, 0);
                a11 = __builtin_amdgcn_mfma_f32_16x16x32_bf16(ahi[1][s], bh1, a11, 0, 0, 0);
                a00 = __builtin_amdgcn_mfma_f32_16x16x32_bf16(ahi[0][s], bl0, a00, 0, 0, 0);
                a10 = __builtin_amdgcn_mfma_f32_16x16x32_bf16(ahi[1][s], bl0, a10, 0, 0, 0);
                a01 = __builtin_amdgcn_mfma_f32_16x16x32_bf16(ahi[0][s], bl1, a01, 0, 0, 0);
                a11 = __builtin_amdgcn_mfma_f32_16x16x32_bf16(ahi[1][s], bl1, a11, 0, 0, 0);
                a00 = __builtin_amdgcn_mfma_f32_16x16x32_bf16(alo[0][s], bh0, a00, 0, 0, 0);
                a10 = __builtin_amdgcn_mfma_f32_16x16x32_bf16(alo[1][s], bh0, a10, 0, 0, 0);
                a01 = __builtin_amdgcn_mfma_f32_16x16x32_bf16(alo[0][s], bh1, a01, 0, 0, 0);
                a11 = __builtin_amdgcn_mfma_f32_16x16x32_bf16(alo[1][s], bh1, a11, 0, 0, 0);
            }
            #pragma unroll
            for (int r = 0; r < 4; ++r) {
                sChunk[lgrp * 4 + r][wg * 32 + lrow]           = 2.0f - 2.0f * a00[r];
                sChunk[16 + lgrp * 4 + r][wg * 32 + lrow]      = 2.0f - 2.0f * a10[r];
                sChunk[lgrp * 4 + r][wg * 32 + 16 + lrow]      = 2.0f - 2.0f * a01[r];
                sChunk[16 + lgrp * 4 + r][wg * 32 + 16 + lrow] = 2.0f - 2.0f * a11[r];
            }
        }
        __syncthreads();

        if (mode == 0) {
            for (int e = tid; e < 512; e += 256) {
                int r = e >> 4;
                int id = sMask[r][e & 15] - cglob;
                if (id >= 0 && id < CHUNK) atomicAdd(&sChunk[r][id], 5.0f);
            }
        } else {
            if (tid < CHUNK)
                sCx[tid] = coords[((size_t)b * NN + cglob + tid) * 2];
            else
                sCy[tid - CHUNK] = coords[((size_t)b * NN + cglob + (tid - CHUNK)) * 2 + 1];
        }
        __syncthreads();

        float rx = 0.f, ry = 0.f;
        if (mode != 0) { rx = sRx[srow]; ry = sRy[srow]; }
        #pragma unroll
        for (int j = 0; j < 16; ++j) {
            int cl = sgrp * 16 + j;
            float v = sChunk[srow][cl];
            if (mode != 0) {
                float dx = rx - sCx[cl], dy = ry - sCy[cl];
                if (dx * dx + dy * dy <= RADIUS2) v += 5.0f;
            }
            if (v < loc[7]) {
                loc[7] = v;
                #pragma unroll
                for (int p = 7; p > 0; --p) {
                    if (loc[p - 1] > loc[p]) {
                        float t = loc[p - 1]; loc[p - 1] = loc[p]; loc[p] = t;
                    }
                }
            }
        }
    }

    // parallel tree merge of the 8 per-thread sorted lists per row
    __syncthreads();
    float* mg = &sChunk[0][0];           // [32][67] alias (2144 < 4128 floats)
    #pragma unroll
    for (int k = 0; k < 8; ++k) mg[srow * 67 + sgrp * 8 + k] = loc[k];
    __syncthreads();
    #pragma unroll
    for (int step = 1; step < 8; step <<= 1) {
        if ((sgrp & (2 * step - 1)) == 0) {
            float a[8], bb[8], o[8];
            #pragma unroll
            for (int k = 0; k < 8; ++k) {
                a[k]  = mg[srow * 67 + sgrp * 8 + k];
                bb[k] = mg[srow * 67 + (sgrp + step) * 8 + k];
            }
            merge8(a, bb, o);
            #pragma unroll
            for (int k = 0; k < 8; ++k) mg[srow * 67 + sgrp * 8 + k] = o[k];
        }
        __syncthreads();
    }
    if (tid < 32) {
        size_t row = (size_t)b * NN + row0 + tid;
        #pragma unroll
        for (int k = 0; k < 8; ++k)
            outP[row * outStride + cs * 8 + k] = mg[tid * 67 + k];
    }
}

// ---------------------------------------------------------------------------
// Per-row finalize: merge partial top-8 lists (8 FOS, 2+2 SOS), hinge (FOS)
// and sqrt-diff (SOS)
// ---------------------------------------------------------------------------
__global__ __launch_bounds__(256) void frow_kernel(
    const float* __restrict__ fosP, const float* __restrict__ sosAP,
    const float* __restrict__ sosBP, const float* __restrict__ pos_sim,
    float* __restrict__ frow, float* __restrict__ srow)
{
    int row = blockIdx.x * 256 + threadIdx.x;
    if (row >= NB * NN) return;

    // FOS: 8 sorted lists of 8
    float La[8][8];
    {
        const float4* fp = (const float4*)(fosP + (size_t)row * 64);
        #pragma unroll
        for (int li = 0; li < 8; ++li) {
            float4 qa = fp[2 * li], qb = fp[2 * li + 1];
            La[li][0] = qa.x; La[li][1] = qa.y; La[li][2] = qa.z; La[li][3] = qa.w;
            La[li][4] = qb.x; La[li][5] = qb.y; La[li][6] = qb.z; La[li][7] = qb.w;
        }
    }
    float t0[8], t1[8], t2[8], t3[8], u0[8], u1[8], m[8];
    merge8(La[0], La[1], t0); merge8(La[2], La[3], t1);
    merge8(La[4], La[5], t2); merge8(La[6], La[7], t3);
    merge8(t0, t1, u0); merge8(t2, t3, u1);
    merge8(u0, u1, m);

    float p = pos_sim[row], fs = 0.f;
    #pragma unroll
    for (int k = 0; k < 8; ++k) {
        float h = fmaxf(p - m[k] + 1.0f, 0.f);
        fs += h * h;
    }

    float l0[8], l1[8];
    float4 q;
    const float4* ap = (const float4*)(sosAP + (size_t)row * 16);
    q = ap[0]; l0[0]=q.x; l0[1]=q.y; l0[2]=q.z; l0[3]=q.w;
    q = ap[1]; l0[4]=q.x; l0[5]=q.y; l0[6]=q.z; l0[7]=q.w;
    q = ap[2]; l1[0]=q.x; l1[1]=q.y; l1[2]=q.z; l1[3]=q.w;
    q = ap[3]; l1[4]=q.x; l1[5]=q.y; l1[6]=q.z; l1[7]=q.w;
    merge8(l0, l1, t0);
    const float4* bp = (const float4*)(sosBP + (size_t)row * 16);
    q = bp[0]; l0[0]=q.x; l0[1]=q.y; l0[2]=q.z; l0[3]=q.w;
    q = bp[1]; l0[4]=q.x; l0[5]=q.y; l0[6]=q.z; l0[7]=q.w;
    q = bp[2]; l1[0]=q.x; l1[1]=q.y; l1[2]=q.z; l1[3]=q.w;
    q = bp[3]; l1[4]=q.x; l1[5]=q.y; l1[6]=q.z; l1[7]=q.w;
    merge8(l0, l1, t1);

    float acc = 0.f;
    #pragma unroll
    for (int k = 0; k < 8; ++k) {
        float d = t0[k] - t1[k];
        acc += d * d;
    }
    frow[row] = fs;
    srow[row] = sqrtf(acc);
}

__global__ __launch_bounds__(256) void freduce_kernel(
    const float* __restrict__ frow, const float* __restrict__ srow,
    float* __restrict__ outp)
{
    __shared__ float sf[256], ss[256];
    int t = threadIdx.x;
    float f = 0.f, s = 0.f;
    for (int i = t; i < NB * NN; i += 256) { f += frow[i]; s += srow[i]; }
    sf[t] = f; ss[t] = s;
    __syncthreads();
    for (int o = 128; o > 0; o >>= 1) {
        if (t < o) { sf[t] += sf[t + o]; ss[t] += ss[t + o]; }
        __syncthreads();
    }
    if (t == 0)
        outp[0] = sf[0] / (float)(NB * NN * 8) + ss[0] / (float)(NB * NN);
}

extern "C" void kernel_launch(void* const* d_in, const int* in_sizes, int n_in,
                              void* d_out, int out_size, void* d_ws, size_t ws_size,
                              hipStream_t stream) {
    const float* kp1      = (const float*)d_in[0];
    const float* w_kp1    = (const float*)d_in[1];
    const float* kp1_desc = (const float*)d_in[2];
    const float* desc2    = (const float*)d_in[3];
    const float* homo     = (const float*)d_in[4];
    float* outp = (float*)d_out;

    char* ws = (char*)d_ws;
    size_t o = 0;
    unsigned short* khi  = (unsigned short*)(ws + o); o += (size_t)NB * NN * NCCH * 2;
    unsigned short* klo  = (unsigned short*)(ws + o); o += (size_t)NB * NN * NCCH * 2;
    unsigned short* whi  = (unsigned short*)(ws + o); o += (size_t)NB * NN * NCCH * 2;
    unsigned short* wlo  = (unsigned short*)(ws + o); o += (size_t)NB * NN * NCCH * 2;
    unsigned short* d2hi = (unsigned short*)(ws + o); o += (size_t)NB * NHW * NCCH * 2;
    unsigned short* d2lo = (unsigned short*)(ws + o); o += (size_t)NB * NHW * NCCH * 2;
    float* pos_sim = (float*)(ws + o); o += (size_t)NB * NN * 4;
    float* fosP    = (float*)(ws + o); o += (size_t)NB * NN * 64 * 4;
    float* sosAP   = (float*)(ws + o); o += (size_t)NB * NN * 16 * 4;
    float* sosBP   = (float*)(ws + o); o += (size_t)NB * NN * 16 * 4;
    float* frow    = (float*)(ws + o); o += (size_t)NB * NN * 4;
    float* srow    = (float*)(ws + o); o += (size_t)NB * NN * 4;
    int*   mask_id = (int*)(ws + o);   o += (size_t)NB * NN * 16 * 4;

    prep_kernel<<<2064, 256, 0, stream>>>(kp1, w_kp1, kp1_desc, desc2, homo,
                                          khi, klo, whi, wlo, d2hi, d2lo,
                                          pos_sim, mask_id);
    simtop_fused<<<1536, 256, 0, stream>>>(khi, klo, whi, wlo, d2hi, d2lo,
                                           kp1, w_kp1, mask_id,
                                           fosP, sosAP, sosBP);
    frow_kernel<<<16, 256, 0, stream>>>(fosP, sosAP, sosBP, pos_sim, frow, srow);
    freduce_kernel<<<1, 256, 0, stream>>>(frow, srow, outp);
}